// Round 9
// baseline (523.743 us; speedup 1.0000x reference)
//
#include <hip/hip_runtime.h>
#include <hip/hip_bf16.h>

#define NN 4608
#define BG 48
#define NPG 96
#define DD 512
#define XDIM 16
#define EREAL 147456
#define NLAYER 6
#define NK 262144     // 512*512
#define TRIU 4656     // 96*97/2

typedef __hip_bfloat16 bf16;
typedef short short8 __attribute__((ext_vector_type(8)));
typedef short shortx4 __attribute__((ext_vector_type(4)));
typedef float f32x4 __attribute__((ext_vector_type(4)));
typedef float f32x2 __attribute__((ext_vector_type(2)));

__device__ __forceinline__ float s2f(short s) {
  return __uint_as_float(((unsigned int)(unsigned short)s) << 16);
}
__device__ __forceinline__ short f2bs(float f) {
  bf16 h = __float2bfloat16(f);
  short s;
  __builtin_memcpy(&s, &h, 2);
  return s;
}
__device__ __forceinline__ void f8x4(unsigned int w, float* o) {
  f32x2 a = __builtin_amdgcn_cvt_pk_f32_fp8(w, false);
  f32x2 b = __builtin_amdgcn_cvt_pk_f32_fp8(w, true);
  o[0] = a[0]; o[1] = a[1]; o[2] = b[0]; o[3] = b[1];
}
__device__ __forceinline__ void bf4(uint2 q, float* o) {
  o[0] = s2f((short)(q.x & 0xffff));
  o[1] = s2f((short)(q.x >> 16));
  o[2] = s2f((short)(q.y & 0xffff));
  o[3] = s2f((short)(q.y >> 16));
}

typedef const __attribute__((address_space(1))) unsigned int ga_u32;
typedef __attribute__((address_space(3))) unsigned int ls_u32;
__device__ __forceinline__ void gl16(const void* g, void* l) {
  __builtin_amdgcn_global_load_lds((ga_u32*)g, (ls_u32*)l, 16, 0, 0);
}

// ---------- weight transpose + bf16 convert; also zero counts & statsAll ----------
__global__ __launch_bounds__(256) void k_wt(const float* __restrict__ wl,
                                            const float* __restrict__ wr,
                                            const float* __restrict__ cg,
                                            const float* __restrict__ lin,
                                            bf16* __restrict__ Wt,
                                            int* __restrict__ counts,
                                            float* __restrict__ statsAll) {
  if (blockIdx.z == 0) {
    int id = (blockIdx.y * 16 + blockIdx.x) * 256 + threadIdx.x;
    if (id < NN) counts[id] = 0;
    if (id < 5 * 32) statsAll[id] = 0.f;
  }
  __shared__ float tile[32][33];
  int z = blockIdx.z;
  const float* src = (z < 6) ? wl + (size_t)z * NK
                   : (z < 12) ? wr + (size_t)(z - 6) * NK
                   : (z == 12) ? cg : lin;
  bf16* dst = Wt + (size_t)z * NK;
  int c = threadIdx.x & 31;
  int r0 = threadIdx.x >> 5;  // 0..7
  int bx = blockIdx.x * 32, by = blockIdx.y * 32;
#pragma unroll
  for (int i = 0; i < 4; i++) {
    int r = r0 + i * 8;
    tile[r][c] = src[(size_t)(by + r) * 512 + bx + c];  // [k][n]
  }
  __syncthreads();
#pragma unroll
  for (int i = 0; i < 4; i++) {
    int r = r0 + i * 8;  // n within tile
    dst[(size_t)(bx + r) * 512 + by + c] = __float2bfloat16(tile[c][r]);
  }
}

// ---------- x projection + edge histogram + cloud edge params ----------
__global__ void k_xproj(const float* __restrict__ x, const float* __restrict__ w,
                        const float* __restrict__ b, const int* __restrict__ ei,
                        const float* __restrict__ xyz,
                        bf16* __restrict__ h_bf, int* __restrict__ counts,
                        float* __restrict__ ep) {
  int i = blockIdx.x * blockDim.x + threadIdx.x;
  if (i >= NN * DD) return;
  if (i < EREAL) atomicAdd(&counts[ei[EREAL + i]], 1);
  if (i < NN * NPG) {
    int n = i / NPG, e = i - n * NPG;
    int p = n % NPG;
    if (e < NPG - p) {
      int g = n / NPG;
      int slot = g * TRIU + p * NPG - (p * (p - 1)) / 2 + e;
      int j = n + e;
      float dx = xyz[n * 3] - xyz[j * 3];
      float dy = xyz[n * 3 + 1] - xyz[j * 3 + 1];
      float dz = xyz[n * 3 + 2] - xyz[j * 3 + 2];
      float sq = dx * dx + dy * dy + dz * dz;
      float dist = (sq > 0.f) ? sqrtf(sq) : 0.f;
      float4 v;
      v.x = dx; v.y = dy; v.z = dz; v.w = __expf(-dist);
      *(float4*)&ep[(size_t)slot * 4] = v;
    }
  }
  int n = i >> 9, d = i & 511;
  float acc = b[d];
#pragma unroll
  for (int k = 0; k < XDIM; k++) acc += x[n * XDIM + k] * w[k * DD + d];
  h_bf[i] = __float2bfloat16(acc);
}

// ---------- edge sort (counting sort by dst) ----------
__global__ void k_scan(const int* __restrict__ counts, int* offsets, int* cursor) {
  __shared__ int part[256];
  int t = threadIdx.x;
  int base = t * 18;  // 4608/256
  int s = 0;
#pragma unroll
  for (int i = 0; i < 18; i++) s += counts[base + i];
  part[t] = s;
  __syncthreads();
  for (int off = 1; off < 256; off <<= 1) {
    int v = part[t];
    int u = (t >= off) ? part[t - off] : 0;
    __syncthreads();
    part[t] = v + u;
    __syncthreads();
  }
  int run = t ? part[t - 1] : 0;
#pragma unroll
  for (int i = 0; i < 18; i++) {
    offsets[base + i] = run;
    cursor[base + i] = run;
    run += counts[base + i];
  }
  if (t == 0) offsets[NN] = EREAL;
}
__global__ void k_scatter(const int* __restrict__ ei, int* cursor, int* ssrc) {
  int e = blockIdx.x * blockDim.x + threadIdx.x;
  if (e < EREAL) {
    int s = ei[e], d = ei[EREAL + e];
    int pos = atomicAdd(&cursor[d], 1);
    ssrc[pos] = s;
  }
}

// ---------- graph-LN + relu, IN PLACE on xg; blocks >= 1152 do col-reduce ----------
__global__ __launch_bounds__(256) void k_ln(bf16* __restrict__ xg,
                                            const float* __restrict__ stats,
                                            const float* __restrict__ g,
                                            const float* __restrict__ b,
                                            const float* __restrict__ p2,
                                            float* __restrict__ colsum,
                                            float* __restrict__ colsq) {
  if ((int)blockIdx.x >= 1152) {  // fused col-reduce segment (l==1 launch only)
    int r0 = (blockIdx.x - 1152) * 32;
    int c0 = threadIdx.x;
    float s0 = 0.f, q0 = 0.f, s1 = 0.f, q1 = 0.f;
    for (int r = r0; r < r0 + 32; ++r) {
      float v = p2[(size_t)r * 512 + c0];
      s0 += v; q0 += v * v;
      float w = p2[(size_t)r * 512 + c0 + 256];
      s1 += w; q1 += w * w;
    }
    atomicAdd(&colsum[c0], s0);
    atomicAdd(&colsq[c0], q0);
    atomicAdd(&colsum[c0 + 256], s1);
    atomicAdd(&colsq[c0 + 256], q1);
    return;
  }
  float s = 0.f, ss = 0.f;
#pragma unroll
  for (int i = 0; i < 16; i++) { s += stats[i]; ss += stats[16 + i]; }
  const float invM = 1.f / ((float)NN * (float)DD);
  float mu = s * invM;
  float var = ss * invM - mu * mu;
  float sd = sqrtf(fmaxf(var, 0.f));
  float inv = 1.f / (sd + 1e-5f);
  int i = blockIdx.x * 256 + threadIdx.x;
  int base = i * 8;
  int d0 = base & 511;
  short8 raw = *(const short8*)&xg[base];
  short8 pk;
#pragma unroll
  for (int k = 0; k < 8; k++) {
    float t = fmaxf((s2f(raw[k]) - mu) * inv * g[d0 + k] + b[d0 + k], 0.f);
    pk[k] = f2bs(t);
  }
  *(short8*)&xg[base] = pk;
}

// ---------- shared GEMM tile body: BK=64 dbuf, XOR-swizzled LDS, swapped MFMA ----
__device__ __forceinline__ void gemm_tile(
    const bf16* __restrict__ Abf, const bf16* __restrict__ B,
    const float* __restrict__ bias,
    float* __restrict__ C, bf16* __restrict__ Cb, unsigned char* __restrict__ Cf8,
    float* __restrict__ csum, float* __restrict__ csq,
    int m0, int n0, bf16* As, bf16* Bs, float* cs, float* cq) {
  int tid = threadIdx.x;
  int lane = tid & 63, wid = tid >> 6;
  int mh = (wid >> 1) * 64, nh = (wid & 1) * 32;
  int l15 = lane & 15, quad = lane >> 4;
  int lr8 = lane >> 3, ls8 = lane & 7;
  int c16l = ls8 ^ lr8;        // inverse-swizzled 16B chunk for staging
  int swzr = (l15 & 7) * 8;    // read-side swizzle term (elements)

  if (csum && tid < 64) { cs[tid] = 0.f; cq[tid] = 0.f; }

  const bf16* aSrc = Abf + (size_t)(m0 + wid * 32 + lr8) * 512 + c16l * 8;
  const bf16* bSrc = B   + (size_t)(n0 + wid * 16 + lr8) * 512 + c16l * 8;

#define STAGE(bi, kt) do {                                                   \
    gl16(aSrc + (kt) * 64,            As + (bi) * 8192 + (wid * 32     ) * 64); \
    gl16(aSrc + (kt) * 64 +  8 * 512, As + (bi) * 8192 + (wid * 32 +  8) * 64); \
    gl16(aSrc + (kt) * 64 + 16 * 512, As + (bi) * 8192 + (wid * 32 + 16) * 64); \
    gl16(aSrc + (kt) * 64 + 24 * 512, As + (bi) * 8192 + (wid * 32 + 24) * 64); \
    gl16(bSrc + (kt) * 64,            Bs + (bi) * 4096 + (wid * 16     ) * 64); \
    gl16(bSrc + (kt) * 64 +  8 * 512, Bs + (bi) * 4096 + (wid * 16 +  8) * 64); \
  } while (0)

  f32x4 acc[4][2];
#pragma unroll
  for (int mt = 0; mt < 4; mt++)
#pragma unroll
    for (int nt = 0; nt < 2; nt++) acc[mt][nt] = (f32x4)0.f;

  STAGE(0, 0);
  __syncthreads();  // drains vmcnt(0) -> buf0 ready

#pragma unroll
  for (int kt = 0; kt < 8; kt++) {
    const int cur = kt & 1;
    if (kt < 7) STAGE(cur ^ 1, kt + 1);  // prefetch overlaps ds_read+MFMA
    short8 af[2][4], bfr[2][2];
#pragma unroll
    for (int kk = 0; kk < 2; kk++) {
#pragma unroll
      for (int mt = 0; mt < 4; mt++)
        af[kk][mt] = *(const short8*)&As[cur * 8192 + (mh + mt * 16 + l15) * 64 +
                                        (((kk * 4 + quad) * 8) ^ swzr)];
#pragma unroll
      for (int nt = 0; nt < 2; nt++)
        bfr[kk][nt] = *(const short8*)&Bs[cur * 4096 + (nh + nt * 16 + l15) * 64 +
                                         (((kk * 4 + quad) * 8) ^ swzr)];
    }
#pragma unroll
    for (int kk = 0; kk < 2; kk++)
#pragma unroll
      for (int mt = 0; mt < 4; mt++)
#pragma unroll
        for (int nt = 0; nt < 2; nt++)
          acc[mt][nt] = __builtin_amdgcn_mfma_f32_16x16x32_bf16(
              bfr[kk][nt], af[kk][mt], acc[mt][nt], 0, 0, 0);
    __syncthreads();
  }
#undef STAGE

  // D-layout (swapped operands): m = mh+mt*16+l15, n = nh+nt*16+quad*4+r
  float colS[2][4] = {{0.f,0.f,0.f,0.f},{0.f,0.f,0.f,0.f}};
  float colQ[2][4] = {{0.f,0.f,0.f,0.f},{0.f,0.f,0.f,0.f}};
  float bv[2][4] = {{0.f,0.f,0.f,0.f},{0.f,0.f,0.f,0.f}};
#pragma unroll
  for (int nt = 0; nt < 2; nt++) {
    if (bias) {
      float4 b4 = *(const float4*)&bias[n0 + nh + nt * 16 + quad * 4];
      bv[nt][0] = b4.x; bv[nt][1] = b4.y; bv[nt][2] = b4.z; bv[nt][3] = b4.w;
    }
  }
#pragma unroll
  for (int mt = 0; mt < 4; mt++) {
    int row = m0 + mh + mt * 16 + l15;
#pragma unroll
    for (int nt = 0; nt < 2; nt++) {
      int col0 = n0 + nh + nt * 16 + quad * 4;
      float v[4];
#pragma unroll
      for (int r2 = 0; r2 < 4; r2++) {
        v[r2] = acc[mt][nt][r2] + bv[nt][r2];
        if (csum) { colS[nt][r2] += v[r2]; colQ[nt][r2] += v[r2] * v[r2]; }
      }
      if (C) {
        float4 o; o.x = v[0]; o.y = v[1]; o.z = v[2]; o.w = v[3];
        *(float4*)&C[(size_t)row * 512 + col0] = o;
      }
      if (Cb) {
        shortx4 o;
#pragma unroll
        for (int r2 = 0; r2 < 4; r2++) o[r2] = f2bs(v[r2]);
        *(shortx4*)&Cb[(size_t)row * 512 + col0] = o;
      }
      if (Cf8) {
        unsigned int u = __builtin_amdgcn_cvt_pk_fp8_f32(v[0], v[1], 0, false);
        u = __builtin_amdgcn_cvt_pk_fp8_f32(v[2], v[3], u, true);
        *(unsigned int*)&Cf8[(size_t)row * 512 + col0] = u;
      }
    }
  }
  if (csum) {
#pragma unroll
    for (int nt = 0; nt < 2; nt++)
#pragma unroll
      for (int r2 = 0; r2 < 4; r2++) {
        atomicAdd(&cs[nh + nt * 16 + quad * 4 + r2], colS[nt][r2]);
        atomicAdd(&cq[nh + nt * 16 + quad * 4 + r2], colQ[nt][r2]);
      }
    __syncthreads();
    if (tid < 64) {
      atomicAdd(&csum[n0 + tid], cs[tid]);
      atomicAdd(&csq[n0 + tid], cq[tid]);
    }
  }
}

// ---------- standalone GEMM (GAT l>=1 and final): nzl=4 (2 B slots) or 3 ----------
__global__ __launch_bounds__(256) void k_gemm(
    const bf16* __restrict__ Abf,
    const bf16* __restrict__ B0, const bf16* __restrict__ B1,
    const float* __restrict__ bias0, const float* __restrict__ bias1,
    float* __restrict__ C0,
    bf16* __restrict__ Cb0, bf16* __restrict__ Cb1,
    unsigned char* __restrict__ Cf8_0,
    float* __restrict__ csum, float* __restrict__ csq, int nzl) {
  __shared__ __align__(16) bf16 As[2 * 128 * 64];
  __shared__ __align__(16) bf16 Bs[2 * 64 * 64];
  __shared__ float cs[64], cq[64];
  int cpx = gridDim.x >> 3;
  int wgid = (blockIdx.x & 7) * cpx + (blockIdx.x >> 3);
  int mi = wgid >> nzl;
  int r = wgid & ((1 << nzl) - 1);
  int z = r >> 3;  // 0 when nzl==3
  int m0 = mi * 128, n0 = (r & 7) * 64;
  gemm_tile(Abf, z ? B1 : B0, z ? bias1 : bias0,
            z ? nullptr : C0, z ? Cb1 : Cb0, z ? nullptr : Cf8_0,
            csum, csq, m0, n0, As, Bs, cs, cq);
}

// ---------- merged l=0 GEMM: GAT xl/xr (576 blocks) + cloud g1 (288 blocks) ----------
__global__ __launch_bounds__(256) void k_gemm_l0(
    const bf16* __restrict__ h_bf,
    const bf16* __restrict__ Bl, const bf16* __restrict__ Br,
    const float* __restrict__ biasl, const float* __restrict__ biasr,
    bf16* __restrict__ xr_bf, unsigned char* __restrict__ xl_f8,
    const bf16* __restrict__ Bg1, bf16* __restrict__ g1_bf,
    float* __restrict__ zptr) {
  __shared__ __align__(16) bf16 As[2 * 128 * 64];
  __shared__ __align__(16) bf16 Bs[2 * 64 * 64];
  int b = blockIdx.x;
  if (b < 576) {  // GAT l=0 segment
    int cpx = 576 >> 3;
    int wgid = (b & 7) * cpx + (b >> 3);
    int mi = wgid >> 4;
    int r = wgid & 15;
    int z = r >> 3;
    int m0 = mi * 128, n0 = (r & 7) * 64;
    gemm_tile(h_bf, z ? Br : Bl, z ? biasr : biasl,
              nullptr, z ? xr_bf : nullptr, z ? nullptr : xl_f8,
              nullptr, nullptr, m0, n0, As, Bs, nullptr, nullptr);
  } else {        // cloud g1 segment (also zeroes colsum/colsq for p2 BN)
    int b2 = b - 576;
    if (b2 == 0) {
      for (int i = threadIdx.x; i < 1024; i += 256) zptr[i] = 0.f;
    }
    int cpx = 288 >> 3;
    int wgid = (b2 & 7) * cpx + (b2 >> 3);
    int mi = wgid >> 3;
    int r = wgid & 7;
    int m0 = mi * 128, n0 = r * 64;
    gemm_tile(h_bf, Bg1, nullptr, nullptr, g1_bf, nullptr,
              nullptr, nullptr, m0, n0, As, Bs, nullptr, nullptr);
  }
}

// ---------- GAT edge block body; optional fused cloud epilogue (l=5) ----------
__device__ __forceinline__ void edge_block(
    const unsigned char* __restrict__ xl8, const bf16* __restrict__ xr,
    const float* __restrict__ att, const float* __restrict__ bias,
    const int* __restrict__ offs, const int* __restrict__ ssrc,
    bf16* __restrict__ out, float* __restrict__ statsOut,
    float* redS, float* redSS,
    // fused cloud-epi args (all null except l=5 dispatch):
    const float* __restrict__ p1, const float* __restrict__ p2,
    const bf16* __restrict__ h_bf,
    const float* __restrict__ colsum, const float* __restrict__ colsq,
    const float* __restrict__ lng, const float* __restrict__ lnb,
    const float* __restrict__ bng, const float* __restrict__ bnb,
    bf16* __restrict__ s_bf, float* __restrict__ zptr) {
  if (zptr && blockIdx.x == 0) {
    for (int i = threadIdx.x; i < 1024; i += 256) zptr[i] = 0.f;
  }
  int wave = (blockIdx.x * blockDim.x + threadIdx.x) >> 6;
  int lane = threadIdx.x & 63;
  int wid = threadIdx.x >> 6;
  if (wave < NN) {
    int n = wave;
    int base = lane * 8;
    float xrv[8], attv[8], acc[8];
    short8 xr8 = *(const short8*)&xr[(size_t)n * 512 + base];
#pragma unroll
    for (int k = 0; k < 8; k++) {
      xrv[k] = s2f(xr8[k]);
      attv[k] = att[base + k];
    }
    float m0, lsum;
    {
      uint2 q = *(const uint2*)&xl8[(size_t)n * 512 + base];
      float xs[8];
      f8x4(q.x, xs);
      f8x4(q.y, xs + 4);
      float sc0 = 0.f;
#pragma unroll
      for (int k = 0; k < 8; k++) {
        acc[k] = xs[k];
        float t = xs[k] + xrv[k];
        t = (t > 0.f) ? t : 0.2f * t;
        sc0 += attv[k] * t;
      }
#pragma unroll
      for (int off = 32; off >= 1; off >>= 1) sc0 += __shfl_xor(sc0, off, 64);
      m0 = sc0;
      lsum = 1.f;
    }
    int e0 = offs[n], e1 = offs[n + 1];
    int e = e0;
    for (; e + 3 < e1; e += 4) {
      int s0 = ssrc[e], s1 = ssrc[e + 1], s2 = ssrc[e + 2], s3 = ssrc[e + 3];
      uint2 q0 = *(const uint2*)&xl8[(size_t)s0 * 512 + base];
      uint2 q1 = *(const uint2*)&xl8[(size_t)s1 * 512 + base];
      uint2 q2 = *(const uint2*)&xl8[(size_t)s2 * 512 + base];
      uint2 q3 = *(const uint2*)&xl8[(size_t)s3 * 512 + base];
      float x0[8], x1[8], x2[8], x3[8];
      f8x4(q0.x, x0); f8x4(q0.y, x0 + 4);
      f8x4(q1.x, x1); f8x4(q1.y, x1 + 4);
      f8x4(q2.x, x2); f8x4(q2.y, x2 + 4);
      f8x4(q3.x, x3); f8x4(q3.y, x3 + 4);
      float c0 = 0.f, c1 = 0.f, c2 = 0.f, c3 = 0.f;
#pragma unroll
      for (int k = 0; k < 8; k++) {
        float t0 = x0[k] + xrv[k]; t0 = (t0 > 0.f) ? t0 : 0.2f * t0; c0 += attv[k] * t0;
        float t1 = x1[k] + xrv[k]; t1 = (t1 > 0.f) ? t1 : 0.2f * t1; c1 += attv[k] * t1;
        float t2 = x2[k] + xrv[k]; t2 = (t2 > 0.f) ? t2 : 0.2f * t2; c2 += attv[k] * t2;
        float t3 = x3[k] + xrv[k]; t3 = (t3 > 0.f) ? t3 : 0.2f * t3; c3 += attv[k] * t3;
      }
#pragma unroll
      for (int off = 32; off >= 1; off >>= 1) {
        c0 += __shfl_xor(c0, off, 64);
        c1 += __shfl_xor(c1, off, 64);
        c2 += __shfl_xor(c2, off, 64);
        c3 += __shfl_xor(c3, off, 64);
      }
      float p0 = __expf(c0 - m0), pp1 = __expf(c1 - m0);
      float pp2 = __expf(c2 - m0), p3 = __expf(c3 - m0);
      lsum += p0 + pp1 + pp2 + p3;
#pragma unroll
      for (int k = 0; k < 8; k++)
        acc[k] += p0 * x0[k] + pp1 * x1[k] + pp2 * x2[k] + p3 * x3[k];
    }
    for (; e < e1; ++e) {
      int s0 = ssrc[e];
      uint2 q = *(const uint2*)&xl8[(size_t)s0 * 512 + base];
      float x0[8];
      f8x4(q.x, x0);
      f8x4(q.y, x0 + 4);
      float sc0 = 0.f;
#pragma unroll
      for (int k = 0; k < 8; k++) {
        float t0 = x0[k] + xrv[k];
        t0 = (t0 > 0.f) ? t0 : 0.2f * t0;
        sc0 += attv[k] * t0;
      }
#pragma unroll
      for (int off = 32; off >= 1; off >>= 1) sc0 += __shfl_xor(sc0, off, 64);
      float p0 = __expf(sc0 - m0);
      lsum += p0;
#pragma unroll
      for (int k = 0; k < 8; k++) acc[k] += p0 * x0[k];
    }
    float inv = 1.f / lsum;
    float o[8];
    float s = 0.f, ss = 0.f;
    short8 o8;
#pragma unroll
    for (int k = 0; k < 8; k++) {
      o[k] = acc[k] * inv + bias[base + k];
      s += o[k];
      ss += o[k] * o[k];
      o8[k] = f2bs(o[k]);
    }
    *(short8*)&out[(size_t)n * 512 + base] = o8;
    if (statsOut) {
#pragma unroll
      for (int off = 32; off >= 1; off >>= 1) {
        s += __shfl_xor(s, off, 64);
        ss += __shfl_xor(ss, off, 64);
      }
      if (lane == 0) { redS[wid] = s; redSS[wid] = ss; }
    }
    if (s_bf) {
      // fused cloud epilogue: ln_row(p1) + bn(p2) + fuse -> s_bf (bit-identical
      // to the standalone version: xg input = s2f(o8) = freshly rounded out)
      size_t rb = (size_t)n * 512 + base;
      float v[8];
      float sp = 0.f;
#pragma unroll
      for (int k = 0; k < 8; k++) {
        v[k] = p1[rb + k];
        sp += v[k];
      }
#pragma unroll
      for (int off = 32; off >= 1; off >>= 1) sp += __shfl_xor(sp, off, 64);
      float mu = sp * (1.f / 512.f);
      float ssp = 0.f;
#pragma unroll
      for (int k = 0; k < 8; k++) {
        float t = v[k] - mu;
        ssp += t * t;
      }
#pragma unroll
      for (int off = 32; off >= 1; off >>= 1) ssp += __shfl_xor(ssp, off, 64);
      float linv = 1.f / sqrtf(ssp * (1.f / 512.f) + 1e-5f);
      short8 hb = *(const short8*)&h_bf[rb];
      short8 e8;
#pragma unroll
      for (int k = 0; k < 8; k++) {
        int d = base + k;
        float ln1 = (v[k] - mu) * linv * lng[d] + lnb[d];
        float cmu = colsum[d] * (1.f / NN);
        float cvar = colsq[d] * (1.f / NN) - cmu * cmu;
        float cinv = 1.f / sqrtf(fmaxf(cvar, 0.f) + 1e-5f);
        float bnv = (p2[rb + k] - cmu) * cinv * bng[d] + bnb[d];
        float outv = 2.f * s2f(hb[k]) + s2f(o8[k]) + ln1 + bnv;
        e8[k] = f2bs(outv);
      }
      *(short8*)&s_bf[rb] = e8;
    }
  }
  if (statsOut) {
    __syncthreads();
    if (threadIdx.x == 0) {
      float a = redS[0] + redS[1] + redS[2] + redS[3];
      float b = redSS[0] + redSS[1] + redSS[2] + redSS[3];
      int slot = blockIdx.x & 15;
      atomicAdd(&statsOut[slot], a);
      atomicAdd(&statsOut[16 + slot], b);
    }
  }
}

// ---------- cloud wave body: BALANCED pair (p, 95-p) per wave, 4 dims/lane ----
__device__ __forceinline__ void cloud_wave(
    const bf16* __restrict__ g1, const float* __restrict__ ep,
    const float* __restrict__ lin1b, const float* __restrict__ w3,
    float* __restrict__ p1, float* __restrict__ p2, int w, int lane) {
  int qh = w & 1;
  int pi = w >> 1;              // [0, 2304)
  int g = pi / 48, pp = pi % 48;
  int d0 = qh * 256 + lane * 4;
  float4 bb4 = *(const float4*)&lin1b[d0];
  float4 w04 = *(const float4*)&w3[d0];
  float4 w14 = *(const float4*)&w3[512 + d0];
  float4 w24 = *(const float4*)&w3[1024 + d0];
  float bb[4] = {bb4.x, bb4.y, bb4.z, bb4.w};
  float w0[4] = {w04.x, w04.y, w04.z, w04.w};
  float w1[4] = {w14.x, w14.y, w14.z, w14.w};
  float w2[4] = {w24.x, w24.y, w24.z, w24.w};

#pragma unroll
  for (int half = 0; half < 2; half++) {
    int p = half ? (NPG - 1 - pp) : pp;
    int n = g * NPG + p;
    int cnt = NPG - p;
    int slot0 = g * TRIU + p * NPG - (p * (p - 1)) / 2;
    const bf16* grow = &g1[(size_t)n * 512 + d0];
    float gi[4];
    { uint2 q = *(const uint2*)grow; bf4(q, gi); }
    float a1[4] = {0.f,0.f,0.f,0.f}, a2[4] = {0.f,0.f,0.f,0.f};
    float b1[4] = {0.f,0.f,0.f,0.f}, b2[4] = {0.f,0.f,0.f,0.f};
    int e = 0;
    for (; e + 3 < cnt; e += 4) {
      int sb = __builtin_amdgcn_readfirstlane(slot0 + e);  // wave-uniform -> s_load
      float4 pa = *(const float4*)&ep[(size_t)sb * 4];
      float4 pb = *(const float4*)&ep[(size_t)(sb + 1) * 4];
      float4 pc = *(const float4*)&ep[(size_t)(sb + 2) * 4];
      float4 pd = *(const float4*)&ep[(size_t)(sb + 3) * 4];
      uint2 qa = *(const uint2*)&grow[(size_t)e * 512];
      uint2 qb = *(const uint2*)&grow[(size_t)(e + 1) * 512];
      uint2 qc = *(const uint2*)&grow[(size_t)(e + 2) * 512];
      uint2 qd = *(const uint2*)&grow[(size_t)(e + 3) * 512];
      float xa[4], xb[4], xc[4], xd[4];
      bf4(qa, xa); bf4(qb, xb); bf4(qc, xc); bf4(qd, xd);
      float t;
#pragma unroll
      for (int k = 0; k < 4; k++) {
        t = fmaf(pa.w, gi[k] - xa[k], bb[k]); a1[k] += fmaxf(t, 0.f);
        t = fmaf(pb.w, gi[k] - xb[k], bb[k]); b1[k] += fmaxf(t, 0.f);
        t = fmaf(pc.w, gi[k] - xc[k], bb[k]); a1[k] += fmaxf(t, 0.f);
        t = fmaf(pd.w, gi[k] - xd[k], bb[k]); b1[k] += fmaxf(t, 0.f);
        t = pa.x * w0[k] + pa.y * w1[k] + pa.z * w2[k]; a2[k] += fmaxf(t, 0.f);
        t = pb.x * w0[k] + pb.y * w1[k] + pb.z * w2[k]; b2[k] += fmaxf(t, 0.f);
        t = pc.x * w0[k] + pc.y * w1[k] + pc.z * w2[k]; a2[k] += fmaxf(t, 0.f);
        t = pd.x * w0[k] + pd.y * w1[k] + pd.z * w2[k]; b2[k] += fmaxf(t, 0.f);
      }
    }
    for (; e < cnt; ++e) {
      float4 pa = *(const float4*)&ep[(size_t)(slot0 + e) * 4];
      uint2 qa = *(const uint2*)&grow[(size_t)e * 512];
      float xa[4];
      bf4(qa, xa);
      float t;
#pragma unroll
      for (int k = 0; k < 4; k++) {
        t = fmaf(pa.w, gi[k] - xa[k], bb[k]); a1[k] += fmaxf(t, 0.f);
        t = pa.x * w0[k] + pa.y * w1[k] + pa.z * w2[k]; a2[k] += fmaxf(t, 0.f);
      }
    }
    float4 o1, o2;
    o1.x = a1[0] + b1[0]; o1.y = a1[1] + b1[1];
    o1.z = a1[2] + b1[2]; o1.w = a1[3] + b1[3];
    o2.x = a2[0] + b2[0]; o2.y = a2[1] + b2[1];
    o2.z = a2[2] + b2[2]; o2.w = a2[3] + b2[3];
    *(float4*)&p1[(size_t)n * 512 + d0] = o1;
    *(float4*)&p2[(size_t)n * 512 + d0] = o2;
  }
}

// ---------- standalone GAT edge (layers 1..5; l=5 fuses cloud epilogue) ----------
__global__ __launch_bounds__(256) void k_gat_edge(
    const unsigned char* __restrict__ xl8, const bf16* __restrict__ xr,
    const float* __restrict__ att, const float* __restrict__ bias,
    const int* __restrict__ offs, const int* __restrict__ ssrc,
    bf16* __restrict__ out, float* __restrict__ statsOut,
    const float* __restrict__ p1, const float* __restrict__ p2,
    const bf16* __restrict__ h_bf,
    const float* __restrict__ colsum, const float* __restrict__ colsq,
    const float* __restrict__ lng, const float* __restrict__ lnb,
    const float* __restrict__ bng, const float* __restrict__ bnb,
    bf16* __restrict__ s_bf, float* __restrict__ zptr) {
  __shared__ float redS[4], redSS[4];
  edge_block(xl8, xr, att, bias, offs, ssrc, out, statsOut, redS, redSS,
             p1, p2, h_bf, colsum, colsq, lng, lnb, bng, bnb, s_bf, zptr);
}

// ---------- merged l=0 edge (1152 blocks) + cloud (1152 blocks, balanced) ----------
__global__ __launch_bounds__(256) void k_edge_cloud(
    const unsigned char* __restrict__ xl8, const bf16* __restrict__ xr,
    const float* __restrict__ att, const float* __restrict__ bias,
    const int* __restrict__ offs, const int* __restrict__ ssrc,
    bf16* __restrict__ out, float* __restrict__ statsOut,
    const bf16* __restrict__ g1, const float* __restrict__ ep,
    const float* __restrict__ lin1b, const float* __restrict__ w3,
    float* __restrict__ p1, float* __restrict__ p2) {
  __shared__ float redS[4], redSS[4];
  if ((int)blockIdx.x < 1152) {
    edge_block(xl8, xr, att, bias, offs, ssrc, out, statsOut, redS, redSS,
               nullptr, nullptr, nullptr, nullptr, nullptr, nullptr, nullptr,
               nullptr, nullptr, nullptr, nullptr);
  } else {
    int w = (blockIdx.x - 1152) * 4 + (threadIdx.x >> 6);
    cloud_wave(g1, ep, lin1b, w3, p1, p2, w, threadIdx.x & 63);
  }
}

__global__ void k_bn_out(const float* __restrict__ y, const float* __restrict__ colsum,
                         const float* __restrict__ colsq, const float* __restrict__ g,
                         const float* __restrict__ b, float* __restrict__ out) {
  int i = blockIdx.x * blockDim.x + threadIdx.x;
  if (i >= NN * DD) return;
  int d = i & 511;
  float mu = colsum[d] * (1.f / NN);
  float var = colsq[d] * (1.f / NN) - mu * mu;
  float inv = 1.f / sqrtf(fmaxf(var, 0.f) + 1e-5f);
  out[i] = (y[i] - mu) * inv * g[d] + b[d];
}

extern "C" void kernel_launch(void* const* d_in, const int* in_sizes, int n_in,
                              void* d_out, int out_size, void* d_ws, size_t ws_size,
                              hipStream_t stream) {
  const float* x = (const float*)d_in[0];
  const int* ei = (const int*)d_in[1];
  const float* xyz = (const float*)d_in[3];
  const float* x_proj_w = (const float*)d_in[5];
  const float* x_proj_b = (const float*)d_in[6];
  const float* gat_wl = (const float*)d_in[7];
  const float* gat_bl = (const float*)d_in[8];
  const float* gat_wr = (const float*)d_in[9];
  const float* gat_br = (const float*)d_in[10];
  const float* gat_att = (const float*)d_in[11];
  const float* gat_bias = (const float*)d_in[12];
  const float* gat_ln_g = (const float*)d_in[13];
  const float* gat_ln_b = (const float*)d_in[14];
  const float* cg_xyz_w = (const float*)d_in[15];
  const float* cg_bn_g = (const float*)d_in[16];
  const float* cg_bn_b = (const float*)d_in[17];
  const float* cg_lin1_w = (const float*)d_in[18];
  const float* cg_lin1_b = (const float*)d_in[19];
  const float* cg_ln_g = (const float*)d_in[20];
  const float* cg_ln_b = (const float*)d_in[21];
  const float* lin_w = (const float*)d_in[22];
  const float* lin_b = (const float*)d_in[23];
  const float* bn_g = (const float*)d_in[24];
  const float* bn_b = (const float*)d_in[25];

  const size_t ND = (size_t)NN * DD;
  char* w = (char*)d_ws;
  float* p1 = (float*)w;       w += ND * 4;  // alias: final y
  float* p2 = (float*)w;       w += ND * 4;
  bf16* h_bf = (bf16*)w;       w += ND * 2;  // alias: s_bf (after fused epi)
  bf16* xg_bf = (bf16*)w;      w += ND * 2;  // LN applied IN PLACE between layers
  bf16* g1_bf = (bf16*)w;      w += ND * 2;
  bf16* xr_bf = (bf16*)w;      w += ND * 2;
  unsigned char* xl_f8 = (unsigned char*)w; w += ND;
  bf16* Wt = (bf16*)w;         w += (size_t)14 * NK * 2;
  float* eparam = (float*)w;   w += (size_t)BG * TRIU * 16;
  int* counts = (int*)w;       w += NN * 4;
  int* offs = (int*)w;         w += (NN + 4) * 4;
  int* cursor = (int*)w;       w += NN * 4;
  int* ssrc = (int*)w;         w += EREAL * 4;
  float* statsAll = (float*)w; w += 5 * 32 * 4;
  float* colsum = (float*)w;   w += 512 * 4;
  float* colsq = (float*)w;    w += 512 * 4;
  float* colsum2 = (float*)w;  w += 512 * 4;
  float* colsq2 = (float*)w;   w += 512 * 4;
  float* y = p1;
  bf16* s_bf = h_bf;

  const int TPB = 256;
  const int ND_BLK = (int)((ND + TPB - 1) / TPB);

  k_wt<<<dim3(16, 16, 14), TPB, 0, stream>>>(gat_wl, gat_wr, cg_lin1_w, lin_w, Wt,
                                             counts, statsAll);
  k_xproj<<<ND_BLK, TPB, 0, stream>>>(x, x_proj_w, x_proj_b, ei, xyz, h_bf,
                                      counts, eparam);
  k_scan<<<1, 256, 0, stream>>>(counts, offs, cursor);
  k_scatter<<<(EREAL + TPB - 1) / TPB, TPB, 0, stream>>>(ei, cursor, ssrc);

  // l=0 GEMM (xl,xr) + cloud g1 GEMM in one dispatch (zeroes colsum/colsq)
  k_gemm_l0<<<864, TPB, 0, stream>>>(h_bf, Wt, Wt + (size_t)6 * NK,
                                     gat_bl, gat_br, xr_bf, xl_f8,
                                     Wt + (size_t)12 * NK, g1_bf, colsum);
  // l=0 edge + balanced cloud in one dispatch (cloud overlaps the GAT stack)
  k_edge_cloud<<<1152 + 1152, TPB, 0, stream>>>(
      xl_f8, xr_bf, gat_att, gat_bias, offs, ssrc, xg_bf, statsAll,
      g1_bf, eparam, cg_lin1_b, cg_xyz_w, p1, p2);

  for (int l = 1; l < NLAYER; l++) {
    // in-place graph-LN (+ fused p2 col-reduce on the l==1 dispatch)
    k_ln<<<(l == 1) ? 1296 : 1152, TPB, 0, stream>>>(
        xg_bf, statsAll + 32 * (l - 1),
        gat_ln_g + (size_t)(l - 1) * DD, gat_ln_b + (size_t)(l - 1) * DD,
        (l == 1) ? p2 : nullptr, colsum, colsq);
    k_gemm<<<576, TPB, 0, stream>>>(
        xg_bf, Wt + (size_t)l * NK, Wt + (size_t)(6 + l) * NK,
        gat_bl + l * DD, gat_br + l * DD, nullptr, nullptr, xr_bf,
        xl_f8, nullptr, nullptr, 4);
    float* sOut = (l < NLAYER - 1) ? statsAll + 32 * l : nullptr;
    bool last = (l == NLAYER - 1);
    k_gat_edge<<<NN / 4, TPB, 0, stream>>>(
        xl_f8, xr_bf, gat_att + l * DD, gat_bias + l * DD, offs, ssrc,
        xg_bf, sOut,
        last ? p1 : nullptr, last ? p2 : nullptr, last ? h_bf : nullptr,
        last ? colsum : nullptr, last ? colsq : nullptr,
        last ? cg_ln_g : nullptr, last ? cg_ln_b : nullptr,
        last ? cg_bn_g : nullptr, last ? cg_bn_b : nullptr,
        last ? s_bf : nullptr, last ? colsum2 : nullptr);
  }

  // final: y = s @ lin_w + lin_b (fp32) with fused column stats -> bn_out
  k_gemm<<<288, TPB, 0, stream>>>(
      s_bf, Wt + (size_t)13 * NK, Wt + (size_t)13 * NK, lin_b, lin_b,
      y, nullptr, nullptr, nullptr, colsum2, colsq2, 3);
  k_bn_out<<<ND_BLK, TPB, 0, stream>>>(y, colsum2, colsq2, bn_g, bn_b,
                                       (float*)d_out);
}

// Round 10
// 511.900 us; speedup vs baseline: 1.0231x; 1.0231x over previous
//
#include <hip/hip_runtime.h>
#include <hip/hip_bf16.h>

#define NN 4608
#define BG 48
#define NPG 96
#define DD 512
#define XDIM 16
#define EREAL 147456
#define NLAYER 6
#define NK 262144     // 512*512
#define TRIU 4656     // 96*97/2

typedef __hip_bfloat16 bf16;
typedef short short8 __attribute__((ext_vector_type(8)));
typedef short shortx4 __attribute__((ext_vector_type(4)));
typedef float f32x4 __attribute__((ext_vector_type(4)));
typedef float f32x2 __attribute__((ext_vector_type(2)));

__device__ __forceinline__ float s2f(short s) {
  return __uint_as_float(((unsigned int)(unsigned short)s) << 16);
}
__device__ __forceinline__ short f2bs(float f) {
  bf16 h = __float2bfloat16(f);
  short s;
  __builtin_memcpy(&s, &h, 2);
  return s;
}
__device__ __forceinline__ void f8x4(unsigned int w, float* o) {
  f32x2 a = __builtin_amdgcn_cvt_pk_f32_fp8(w, false);
  f32x2 b = __builtin_amdgcn_cvt_pk_f32_fp8(w, true);
  o[0] = a[0]; o[1] = a[1]; o[2] = b[0]; o[3] = b[1];
}

typedef const __attribute__((address_space(1))) unsigned int ga_u32;
typedef __attribute__((address_space(3))) unsigned int ls_u32;
__device__ __forceinline__ void gl16(const void* g, void* l) {
  __builtin_amdgcn_global_load_lds((ga_u32*)g, (ls_u32*)l, 16, 0, 0);
}

// ---------- weight transpose + bf16 convert; also zero counts & statsAll ----------
__global__ __launch_bounds__(256) void k_wt(const float* __restrict__ wl,
                                            const float* __restrict__ wr,
                                            const float* __restrict__ cg,
                                            const float* __restrict__ lin,
                                            bf16* __restrict__ Wt,
                                            int* __restrict__ counts,
                                            float* __restrict__ statsAll) {
  if (blockIdx.z == 0) {
    int id = (blockIdx.y * 16 + blockIdx.x) * 256 + threadIdx.x;
    if (id < NN) counts[id] = 0;
    if (id < 5 * 32) statsAll[id] = 0.f;
  }
  __shared__ float tile[32][33];
  int z = blockIdx.z;
  const float* src = (z < 6) ? wl + (size_t)z * NK
                   : (z < 12) ? wr + (size_t)(z - 6) * NK
                   : (z == 12) ? cg : lin;
  bf16* dst = Wt + (size_t)z * NK;
  int c = threadIdx.x & 31;
  int r0 = threadIdx.x >> 5;  // 0..7
  int bx = blockIdx.x * 32, by = blockIdx.y * 32;
#pragma unroll
  for (int i = 0; i < 4; i++) {
    int r = r0 + i * 8;
    tile[r][c] = src[(size_t)(by + r) * 512 + bx + c];  // [k][n]
  }
  __syncthreads();
#pragma unroll
  for (int i = 0; i < 4; i++) {
    int r = r0 + i * 8;  // n within tile
    dst[(size_t)(bx + r) * 512 + by + c] = __float2bfloat16(tile[c][r]);
  }
}

// ---------- x projection + edge histogram + cloud edge params ----------
__global__ void k_xproj(const float* __restrict__ x, const float* __restrict__ w,
                        const float* __restrict__ b, const int* __restrict__ ei,
                        const float* __restrict__ xyz,
                        bf16* __restrict__ h_bf, int* __restrict__ counts,
                        float* __restrict__ ep) {
  int i = blockIdx.x * blockDim.x + threadIdx.x;
  if (i >= NN * DD) return;
  if (i < EREAL) atomicAdd(&counts[ei[EREAL + i]], 1);
  if (i < NN * NPG) {
    int n = i / NPG, e = i - n * NPG;
    int p = n % NPG;
    if (e < NPG - p) {
      int g = n / NPG;
      int slot = g * TRIU + p * NPG - (p * (p - 1)) / 2 + e;
      int j = n + e;
      float dx = xyz[n * 3] - xyz[j * 3];
      float dy = xyz[n * 3 + 1] - xyz[j * 3 + 1];
      float dz = xyz[n * 3 + 2] - xyz[j * 3 + 2];
      float sq = dx * dx + dy * dy + dz * dz;
      float dist = (sq > 0.f) ? sqrtf(sq) : 0.f;
      float4 v;
      v.x = dx; v.y = dy; v.z = dz; v.w = __expf(-dist);
      *(float4*)&ep[(size_t)slot * 4] = v;
    }
  }
  int n = i >> 9, d = i & 511;
  float acc = b[d];
#pragma unroll
  for (int k = 0; k < XDIM; k++) acc += x[n * XDIM + k] * w[k * DD + d];
  h_bf[i] = __float2bfloat16(acc);
}

// ---------- edge sort: prefix scan of counts ----------
__global__ void k_scan(const int* __restrict__ counts, int* offsets, int* cursor) {
  __shared__ int part[256];
  int t = threadIdx.x;
  int base = t * 18;  // 4608/256
  int s = 0;
#pragma unroll
  for (int i = 0; i < 18; i++) s += counts[base + i];
  part[t] = s;
  __syncthreads();
  for (int off = 1; off < 256; off <<= 1) {
    int v = part[t];
    int u = (t >= off) ? part[t - off] : 0;
    __syncthreads();
    part[t] = v + u;
    __syncthreads();
  }
  int run = t ? part[t - 1] : 0;
#pragma unroll
  for (int i = 0; i < 18; i++) {
    offsets[base + i] = run;
    cursor[base + i] = run;
    run += counts[base + i];
  }
  if (t == 0) offsets[NN] = EREAL;
}

// ---------- graph-LN + relu, IN PLACE on xg; blocks >= 1152 do col-reduce ----------
// col-reduce sums the two cloud partial buffers: p2 = p2a + p2b.
__global__ __launch_bounds__(256) void k_ln(bf16* __restrict__ xg,
                                            const float* __restrict__ stats,
                                            const float* __restrict__ g,
                                            const float* __restrict__ b,
                                            const float* __restrict__ p2a,
                                            const float* __restrict__ p2b,
                                            float* __restrict__ colsum,
                                            float* __restrict__ colsq) {
  if ((int)blockIdx.x >= 1152) {  // fused col-reduce segment (l==1 launch only)
    int r0 = (blockIdx.x - 1152) * 32;
    int c0 = threadIdx.x;
    float s0 = 0.f, q0 = 0.f, s1 = 0.f, q1 = 0.f;
    for (int r = r0; r < r0 + 32; ++r) {
      float v = p2a[(size_t)r * 512 + c0] + p2b[(size_t)r * 512 + c0];
      s0 += v; q0 += v * v;
      float w = p2a[(size_t)r * 512 + c0 + 256] + p2b[(size_t)r * 512 + c0 + 256];
      s1 += w; q1 += w * w;
    }
    atomicAdd(&colsum[c0], s0);
    atomicAdd(&colsq[c0], q0);
    atomicAdd(&colsum[c0 + 256], s1);
    atomicAdd(&colsq[c0 + 256], q1);
    return;
  }
  float s = 0.f, ss = 0.f;
#pragma unroll
  for (int i = 0; i < 16; i++) { s += stats[i]; ss += stats[16 + i]; }
  const float invM = 1.f / ((float)NN * (float)DD);
  float mu = s * invM;
  float var = ss * invM - mu * mu;
  float sd = sqrtf(fmaxf(var, 0.f));
  float inv = 1.f / (sd + 1e-5f);
  int i = blockIdx.x * 256 + threadIdx.x;
  int base = i * 8;
  int d0 = base & 511;
  short8 raw = *(const short8*)&xg[base];
  short8 pk;
#pragma unroll
  for (int k = 0; k < 8; k++) {
    float t = fmaxf((s2f(raw[k]) - mu) * inv * g[d0 + k] + b[d0 + k], 0.f);
    pk[k] = f2bs(t);
  }
  *(short8*)&xg[base] = pk;
}

// ---------- shared GEMM tile body: BK=64 dbuf, XOR-swizzled LDS, swapped MFMA ----
__device__ __forceinline__ void gemm_tile(
    const bf16* __restrict__ Abf, const bf16* __restrict__ B,
    const float* __restrict__ bias,
    float* __restrict__ C, bf16* __restrict__ Cb, unsigned char* __restrict__ Cf8,
    float* __restrict__ csum, float* __restrict__ csq,
    int m0, int n0, bf16* As, bf16* Bs, float* cs, float* cq) {
  int tid = threadIdx.x;
  int lane = tid & 63, wid = tid >> 6;
  int mh = (wid >> 1) * 64, nh = (wid & 1) * 32;
  int l15 = lane & 15, quad = lane >> 4;
  int lr8 = lane >> 3, ls8 = lane & 7;
  int c16l = ls8 ^ lr8;        // inverse-swizzled 16B chunk for staging
  int swzr = (l15 & 7) * 8;    // read-side swizzle term (elements)

  if (csum && tid < 64) { cs[tid] = 0.f; cq[tid] = 0.f; }

  const bf16* aSrc = Abf + (size_t)(m0 + wid * 32 + lr8) * 512 + c16l * 8;
  const bf16* bSrc = B   + (size_t)(n0 + wid * 16 + lr8) * 512 + c16l * 8;

#define STAGE(bi, kt) do {                                                   \
    gl16(aSrc + (kt) * 64,            As + (bi) * 8192 + (wid * 32     ) * 64); \
    gl16(aSrc + (kt) * 64 +  8 * 512, As + (bi) * 8192 + (wid * 32 +  8) * 64); \
    gl16(aSrc + (kt) * 64 + 16 * 512, As + (bi) * 8192 + (wid * 32 + 16) * 64); \
    gl16(aSrc + (kt) * 64 + 24 * 512, As + (bi) * 8192 + (wid * 32 + 24) * 64); \
    gl16(bSrc + (kt) * 64,            Bs + (bi) * 4096 + (wid * 16     ) * 64); \
    gl16(bSrc + (kt) * 64 +  8 * 512, Bs + (bi) * 4096 + (wid * 16 +  8) * 64); \
  } while (0)

  f32x4 acc[4][2];
#pragma unroll
  for (int mt = 0; mt < 4; mt++)
#pragma unroll
    for (int nt = 0; nt < 2; nt++) acc[mt][nt] = (f32x4)0.f;

  STAGE(0, 0);
  __syncthreads();  // drains vmcnt(0) -> buf0 ready

#pragma unroll
  for (int kt = 0; kt < 8; kt++) {
    const int cur = kt & 1;
    if (kt < 7) STAGE(cur ^ 1, kt + 1);  // prefetch overlaps ds_read+MFMA
    short8 af[2][4], bfr[2][2];
#pragma unroll
    for (int kk = 0; kk < 2; kk++) {
#pragma unroll
      for (int mt = 0; mt < 4; mt++)
        af[kk][mt] = *(const short8*)&As[cur * 8192 + (mh + mt * 16 + l15) * 64 +
                                        (((kk * 4 + quad) * 8) ^ swzr)];
#pragma unroll
      for (int nt = 0; nt < 2; nt++)
        bfr[kk][nt] = *(const short8*)&Bs[cur * 4096 + (nh + nt * 16 + l15) * 64 +
                                         (((kk * 4 + quad) * 8) ^ swzr)];
    }
#pragma unroll
    for (int kk = 0; kk < 2; kk++)
#pragma unroll
      for (int mt = 0; mt < 4; mt++)
#pragma unroll
        for (int nt = 0; nt < 2; nt++)
          acc[mt][nt] = __builtin_amdgcn_mfma_f32_16x16x32_bf16(
              bfr[kk][nt], af[kk][mt], acc[mt][nt], 0, 0, 0);
    __syncthreads();
  }
#undef STAGE

  // D-layout (swapped operands): m = mh+mt*16+l15, n = nh+nt*16+quad*4+r
  float colS[2][4] = {{0.f,0.f,0.f,0.f},{0.f,0.f,0.f,0.f}};
  float colQ[2][4] = {{0.f,0.f,0.f,0.f},{0.f,0.f,0.f,0.f}};
  float bv[2][4] = {{0.f,0.f,0.f,0.f},{0.f,0.f,0.f,0.f}};
#pragma unroll
  for (int nt = 0; nt < 2; nt++) {
    if (bias) {
      float4 b4 = *(const float4*)&bias[n0 + nh + nt * 16 + quad * 4];
      bv[nt][0] = b4.x; bv[nt][1] = b4.y; bv[nt][2] = b4.z; bv[nt][3] = b4.w;
    }
  }
#pragma unroll
  for (int mt = 0; mt < 4; mt++) {
    int row = m0 + mh + mt * 16 + l15;
#pragma unroll
    for (int nt = 0; nt < 2; nt++) {
      int col0 = n0 + nh + nt * 16 + quad * 4;
      float v[4];
#pragma unroll
      for (int r2 = 0; r2 < 4; r2++) {
        v[r2] = acc[mt][nt][r2] + bv[nt][r2];
        if (csum) { colS[nt][r2] += v[r2]; colQ[nt][r2] += v[r2] * v[r2]; }
      }
      if (C) {
        float4 o; o.x = v[0]; o.y = v[1]; o.z = v[2]; o.w = v[3];
        *(float4*)&C[(size_t)row * 512 + col0] = o;
      }
      if (Cb) {
        shortx4 o;
#pragma unroll
        for (int r2 = 0; r2 < 4; r2++) o[r2] = f2bs(v[r2]);
        *(shortx4*)&Cb[(size_t)row * 512 + col0] = o;
      }
      if (Cf8) {
        unsigned int u = __builtin_amdgcn_cvt_pk_fp8_f32(v[0], v[1], 0, false);
        u = __builtin_amdgcn_cvt_pk_fp8_f32(v[2], v[3], u, true);
        *(unsigned int*)&Cf8[(size_t)row * 512 + col0] = u;
      }
    }
  }
  if (csum) {
#pragma unroll
    for (int nt = 0; nt < 2; nt++)
#pragma unroll
      for (int r2 = 0; r2 < 4; r2++) {
        atomicAdd(&cs[nh + nt * 16 + quad * 4 + r2], colS[nt][r2]);
        atomicAdd(&cq[nh + nt * 16 + quad * 4 + r2], colQ[nt][r2]);
      }
    __syncthreads();
    if (tid < 64) {
      atomicAdd(&csum[n0 + tid], cs[tid]);
      atomicAdd(&csq[n0 + tid], cq[tid]);
    }
  }
}

// ---------- standalone GEMM (GAT l>=1 and final): nzl=4 (2 B slots) or 3 ----------
__global__ __launch_bounds__(256) void k_gemm(
    const bf16* __restrict__ Abf,
    const bf16* __restrict__ B0, const bf16* __restrict__ B1,
    const float* __restrict__ bias0, const float* __restrict__ bias1,
    float* __restrict__ C0,
    bf16* __restrict__ Cb0, bf16* __restrict__ Cb1,
    unsigned char* __restrict__ Cf8_0,
    float* __restrict__ csum, float* __restrict__ csq, int nzl) {
  __shared__ __align__(16) bf16 As[2 * 128 * 64];
  __shared__ __align__(16) bf16 Bs[2 * 64 * 64];
  __shared__ float cs[64], cq[64];
  int cpx = gridDim.x >> 3;
  int wgid = (blockIdx.x & 7) * cpx + (blockIdx.x >> 3);
  int mi = wgid >> nzl;
  int r = wgid & ((1 << nzl) - 1);
  int z = r >> 3;  // 0 when nzl==3
  int m0 = mi * 128, n0 = (r & 7) * 64;
  gemm_tile(Abf, z ? B1 : B0, z ? bias1 : bias0,
            z ? nullptr : C0, z ? Cb1 : Cb0, z ? nullptr : Cf8_0,
            csum, csq, m0, n0, As, Bs, cs, cq);
}

// ---------- merged l=0 dispatch: GAT xl/xr (576) + cloud g1 f32 (288) + scatter (576) ----
__global__ __launch_bounds__(256) void k_gemm_l0(
    const bf16* __restrict__ h_bf,
    const bf16* __restrict__ Bl, const bf16* __restrict__ Br,
    const float* __restrict__ biasl, const float* __restrict__ biasr,
    bf16* __restrict__ xr_bf, unsigned char* __restrict__ xl_f8,
    const bf16* __restrict__ Bg1, float* __restrict__ g1f,
    float* __restrict__ zptr,
    const int* __restrict__ ei, int* __restrict__ cursor, int* __restrict__ ssrc) {
  __shared__ __align__(16) bf16 As[2 * 128 * 64];
  __shared__ __align__(16) bf16 Bs[2 * 64 * 64];
  int b = blockIdx.x;
  if (b < 576) {  // GAT l=0 segment
    int cpx = 576 >> 3;
    int wgid = (b & 7) * cpx + (b >> 3);
    int mi = wgid >> 4;
    int r = wgid & 15;
    int z = r >> 3;
    int m0 = mi * 128, n0 = (r & 7) * 64;
    gemm_tile(h_bf, z ? Br : Bl, z ? biasr : biasl,
              nullptr, z ? xr_bf : nullptr, z ? nullptr : xl_f8,
              nullptr, nullptr, m0, n0, As, Bs, nullptr, nullptr);
  } else if (b < 864) {  // cloud g1 segment, f32 out (also zeroes colsum/colsq)
    int b2 = b - 576;
    if (b2 == 0) {
      for (int i = threadIdx.x; i < 1024; i += 256) zptr[i] = 0.f;
    }
    int cpx = 288 >> 3;
    int wgid = (b2 & 7) * cpx + (b2 >> 3);
    int mi = wgid >> 3;
    int r = wgid & 7;
    int m0 = mi * 128, n0 = r * 64;
    gemm_tile(h_bf, Bg1, nullptr, g1f, nullptr, nullptr,
              nullptr, nullptr, m0, n0, As, Bs, nullptr, nullptr);
  } else {  // counting-sort scatter segment (576 blocks x 256 = EREAL)
    int e = (b - 864) * 256 + threadIdx.x;
    int s = ei[e], d = ei[EREAL + e];
    int pos = atomicAdd(&cursor[d], 1);
    ssrc[pos] = s;
  }
}

// ---------- GAT edge block body; optional fused cloud epilogue (l=5) ----------
__device__ __forceinline__ void edge_block(
    const unsigned char* __restrict__ xl8, const bf16* __restrict__ xr,
    const float* __restrict__ att, const float* __restrict__ bias,
    const int* __restrict__ offs, const int* __restrict__ ssrc,
    bf16* __restrict__ out, float* __restrict__ statsOut,
    float* redS, float* redSS,
    // fused cloud-epi args (all null except l=5 dispatch):
    const float* __restrict__ p1a, const float* __restrict__ p1b,
    const float* __restrict__ p2a, const float* __restrict__ p2b,
    const bf16* __restrict__ h_bf,
    const float* __restrict__ colsum, const float* __restrict__ colsq,
    const float* __restrict__ lng, const float* __restrict__ lnb,
    const float* __restrict__ bng, const float* __restrict__ bnb,
    bf16* __restrict__ s_bf, float* __restrict__ zptr) {
  if (zptr && blockIdx.x == 0) {
    for (int i = threadIdx.x; i < 1024; i += 256) zptr[i] = 0.f;
  }
  int wave = (blockIdx.x * blockDim.x + threadIdx.x) >> 6;
  int lane = threadIdx.x & 63;
  int wid = threadIdx.x >> 6;
  if (wave < NN) {
    int n = wave;
    int base = lane * 8;
    float xrv[8], attv[8], acc[8];
    short8 xr8 = *(const short8*)&xr[(size_t)n * 512 + base];
#pragma unroll
    for (int k = 0; k < 8; k++) {
      xrv[k] = s2f(xr8[k]);
      attv[k] = att[base + k];
    }
    float m0, lsum;
    {
      uint2 q = *(const uint2*)&xl8[(size_t)n * 512 + base];
      float xs[8];
      f8x4(q.x, xs);
      f8x4(q.y, xs + 4);
      float sc0 = 0.f;
#pragma unroll
      for (int k = 0; k < 8; k++) {
        acc[k] = xs[k];
        float t = xs[k] + xrv[k];
        t = (t > 0.f) ? t : 0.2f * t;
        sc0 += attv[k] * t;
      }
#pragma unroll
      for (int off = 32; off >= 1; off >>= 1) sc0 += __shfl_xor(sc0, off, 64);
      m0 = sc0;
      lsum = 1.f;
    }
    int e0 = offs[n], e1 = offs[n + 1];
    int e = e0;
    for (; e + 3 < e1; e += 4) {
      int s0 = ssrc[e], s1 = ssrc[e + 1], s2 = ssrc[e + 2], s3 = ssrc[e + 3];
      uint2 q0 = *(const uint2*)&xl8[(size_t)s0 * 512 + base];
      uint2 q1 = *(const uint2*)&xl8[(size_t)s1 * 512 + base];
      uint2 q2 = *(const uint2*)&xl8[(size_t)s2 * 512 + base];
      uint2 q3 = *(const uint2*)&xl8[(size_t)s3 * 512 + base];
      float x0[8], x1[8], x2[8], x3[8];
      f8x4(q0.x, x0); f8x4(q0.y, x0 + 4);
      f8x4(q1.x, x1); f8x4(q1.y, x1 + 4);
      f8x4(q2.x, x2); f8x4(q2.y, x2 + 4);
      f8x4(q3.x, x3); f8x4(q3.y, x3 + 4);
      float c0 = 0.f, c1 = 0.f, c2 = 0.f, c3 = 0.f;
#pragma unroll
      for (int k = 0; k < 8; k++) {
        float t0 = x0[k] + xrv[k]; t0 = (t0 > 0.f) ? t0 : 0.2f * t0; c0 += attv[k] * t0;
        float t1 = x1[k] + xrv[k]; t1 = (t1 > 0.f) ? t1 : 0.2f * t1; c1 += attv[k] * t1;
        float t2 = x2[k] + xrv[k]; t2 = (t2 > 0.f) ? t2 : 0.2f * t2; c2 += attv[k] * t2;
        float t3 = x3[k] + xrv[k]; t3 = (t3 > 0.f) ? t3 : 0.2f * t3; c3 += attv[k] * t3;
      }
#pragma unroll
      for (int off = 32; off >= 1; off >>= 1) {
        c0 += __shfl_xor(c0, off, 64);
        c1 += __shfl_xor(c1, off, 64);
        c2 += __shfl_xor(c2, off, 64);
        c3 += __shfl_xor(c3, off, 64);
      }
      float p0 = __expf(c0 - m0), pp1 = __expf(c1 - m0);
      float pp2 = __expf(c2 - m0), p3 = __expf(c3 - m0);
      lsum += p0 + pp1 + pp2 + p3;
#pragma unroll
      for (int k = 0; k < 8; k++)
        acc[k] += p0 * x0[k] + pp1 * x1[k] + pp2 * x2[k] + p3 * x3[k];
    }
    for (; e < e1; ++e) {
      int s0 = ssrc[e];
      uint2 q = *(const uint2*)&xl8[(size_t)s0 * 512 + base];
      float x0[8];
      f8x4(q.x, x0);
      f8x4(q.y, x0 + 4);
      float sc0 = 0.f;
#pragma unroll
      for (int k = 0; k < 8; k++) {
        float t0 = x0[k] + xrv[k];
        t0 = (t0 > 0.f) ? t0 : 0.2f * t0;
        sc0 += attv[k] * t0;
      }
#pragma unroll
      for (int off = 32; off >= 1; off >>= 1) sc0 += __shfl_xor(sc0, off, 64);
      float p0 = __expf(sc0 - m0);
      lsum += p0;
#pragma unroll
      for (int k = 0; k < 8; k++) acc[k] += p0 * x0[k];
    }
    float inv = 1.f / lsum;
    float o[8];
    float s = 0.f, ss = 0.f;
    short8 o8;
#pragma unroll
    for (int k = 0; k < 8; k++) {
      o[k] = acc[k] * inv + bias[base + k];
      s += o[k];
      ss += o[k] * o[k];
      o8[k] = f2bs(o[k]);
    }
    *(short8*)&out[(size_t)n * 512 + base] = o8;
    if (statsOut) {
#pragma unroll
      for (int off = 32; off >= 1; off >>= 1) {
        s += __shfl_xor(s, off, 64);
        ss += __shfl_xor(ss, off, 64);
      }
      if (lane == 0) { redS[wid] = s; redSS[wid] = ss; }
    }
    if (s_bf) {
      // fused cloud epilogue: ln_row(p1a+p1b) + bn(p2a+p2b) + fuse -> s_bf
      size_t rb = (size_t)n * 512 + base;
      float v[8];
      float sp = 0.f;
#pragma unroll
      for (int k = 0; k < 8; k++) {
        v[k] = p1a[rb + k] + p1b[rb + k];
        sp += v[k];
      }
#pragma unroll
      for (int off = 32; off >= 1; off >>= 1) sp += __shfl_xor(sp, off, 64);
      float mu = sp * (1.f / 512.f);
      float ssp = 0.f;
#pragma unroll
      for (int k = 0; k < 8; k++) {
        float t = v[k] - mu;
        ssp += t * t;
      }
#pragma unroll
      for (int off = 32; off >= 1; off >>= 1) ssp += __shfl_xor(ssp, off, 64);
      float linv = 1.f / sqrtf(ssp * (1.f / 512.f) + 1e-5f);
      short8 hb = *(const short8*)&h_bf[rb];
      short8 e8;
#pragma unroll
      for (int k = 0; k < 8; k++) {
        int d = base + k;
        float ln1 = (v[k] - mu) * linv * lng[d] + lnb[d];
        float cmu = colsum[d] * (1.f / NN);
        float cvar = colsq[d] * (1.f / NN) - cmu * cmu;
        float cinv = 1.f / sqrtf(fmaxf(cvar, 0.f) + 1e-5f);
        float p2v = p2a[rb + k] + p2b[rb + k];
        float bnv = (p2v - cmu) * cinv * bng[d] + bnb[d];
        float outv = 2.f * s2f(hb[k]) + s2f(o8[k]) + ln1 + bnv;
        e8[k] = f2bs(outv);
      }
      *(short8*)&s_bf[rb] = e8;
    }
  }
  if (statsOut) {
    __syncthreads();
    if (threadIdx.x == 0) {
      float a = redS[0] + redS[1] + redS[2] + redS[3];
      float b = redSS[0] + redSS[1] + redSS[2] + redSS[3];
      int slot = blockIdx.x & 15;
      atomicAdd(&statsOut[slot], a);
      atomicAdd(&statsOut[16 + slot], b);
    }
  }
}

// ---------- cloud wave body: (pair, qh, chunk) per wave; f32 g1; 4 dims/lane ----
// chunk c splits each node's edge list [0,h) / [h,cnt) -> disjoint partial bufs.
__device__ __forceinline__ void cloud_wave(
    const float* __restrict__ g1f, const float* __restrict__ ep,
    const float* __restrict__ lin1b, const float* __restrict__ w3,
    float* __restrict__ p1c, float* __restrict__ p2c, int w, int lane) {
  int qh = w & 1;
  int c = (w >> 1) & 1;
  int pi = w >> 2;              // [0, 2304)
  int g = pi / 48, pp = pi % 48;
  int d0 = qh * 256 + lane * 4;
  float4 bb4 = *(const float4*)&lin1b[d0];
  float4 w04 = *(const float4*)&w3[d0];
  float4 w14 = *(const float4*)&w3[512 + d0];
  float4 w24 = *(const float4*)&w3[1024 + d0];
  float bb[4] = {bb4.x, bb4.y, bb4.z, bb4.w};
  float w0[4] = {w04.x, w04.y, w04.z, w04.w};
  float w1[4] = {w14.x, w14.y, w14.z, w14.w};
  float w2[4] = {w24.x, w24.y, w24.z, w24.w};

#pragma unroll
  for (int half = 0; half < 2; half++) {
    int p = half ? (NPG - 1 - pp) : pp;
    int n = g * NPG + p;
    int cnt = NPG - p;
    int h = cnt >> 1;
    int eBeg = c ? h : 0;
    int eEnd = c ? cnt : h;
    int slot0 = g * TRIU + p * NPG - (p * (p - 1)) / 2;
    const float* grow = &g1f[(size_t)n * 512 + d0];
    float4 g4 = *(const float4*)grow;
    float gi[4] = {g4.x, g4.y, g4.z, g4.w};
    float a1[4] = {0.f,0.f,0.f,0.f}, a2[4] = {0.f,0.f,0.f,0.f};
    float b1[4] = {0.f,0.f,0.f,0.f}, b2[4] = {0.f,0.f,0.f,0.f};
    int e = eBeg;
    for (; e + 3 < eEnd; e += 4) {
      int sb = __builtin_amdgcn_readfirstlane(slot0 + e);  // wave-uniform -> s_load
      float4 pa = *(const float4*)&ep[(size_t)sb * 4];
      float4 pb = *(const float4*)&ep[(size_t)(sb + 1) * 4];
      float4 pc = *(const float4*)&ep[(size_t)(sb + 2) * 4];
      float4 pd = *(const float4*)&ep[(size_t)(sb + 3) * 4];
      float4 xa = *(const float4*)&grow[(size_t)e * 512];
      float4 xb = *(const float4*)&grow[(size_t)(e + 1) * 512];
      float4 xc = *(const float4*)&grow[(size_t)(e + 2) * 512];
      float4 xd = *(const float4*)&grow[(size_t)(e + 3) * 512];
      float xaf[4] = {xa.x, xa.y, xa.z, xa.w};
      float xbf[4] = {xb.x, xb.y, xb.z, xb.w};
      float xcf[4] = {xc.x, xc.y, xc.z, xc.w};
      float xdf[4] = {xd.x, xd.y, xd.z, xd.w};
      float t;
#pragma unroll
      for (int k = 0; k < 4; k++) {
        t = fmaf(pa.w, gi[k] - xaf[k], bb[k]); a1[k] += fmaxf(t, 0.f);
        t = fmaf(pb.w, gi[k] - xbf[k], bb[k]); b1[k] += fmaxf(t, 0.f);
        t = fmaf(pc.w, gi[k] - xcf[k], bb[k]); a1[k] += fmaxf(t, 0.f);
        t = fmaf(pd.w, gi[k] - xdf[k], bb[k]); b1[k] += fmaxf(t, 0.f);
        t = pa.x * w0[k] + pa.y * w1[k] + pa.z * w2[k]; a2[k] += fmaxf(t, 0.f);
        t = pb.x * w0[k] + pb.y * w1[k] + pb.z * w2[k]; b2[k] += fmaxf(t, 0.f);
        t = pc.x * w0[k] + pc.y * w1[k] + pc.z * w2[k]; a2[k] += fmaxf(t, 0.f);
        t = pd.x * w0[k] + pd.y * w1[k] + pd.z * w2[k]; b2[k] += fmaxf(t, 0.f);
      }
    }
    for (; e < eEnd; ++e) {
      float4 pa = *(const float4*)&ep[(size_t)(slot0 + e) * 4];
      float4 xa = *(const float4*)&grow[(size_t)e * 512];
      float xaf[4] = {xa.x, xa.y, xa.z, xa.w};
      float t;
#pragma unroll
      for (int k = 0; k < 4; k++) {
        t = fmaf(pa.w, gi[k] - xaf[k], bb[k]); a1[k] += fmaxf(t, 0.f);
        t = pa.x * w0[k] + pa.y * w1[k] + pa.z * w2[k]; a2[k] += fmaxf(t, 0.f);
      }
    }
    float4 o1, o2;
    o1.x = a1[0] + b1[0]; o1.y = a1[1] + b1[1];
    o1.z = a1[2] + b1[2]; o1.w = a1[3] + b1[3];
    o2.x = a2[0] + b2[0]; o2.y = a2[1] + b2[1];
    o2.z = a2[2] + b2[2]; o2.w = a2[3] + b2[3];
    *(float4*)&p1c[(size_t)n * 512 + d0] = o1;
    *(float4*)&p2c[(size_t)n * 512 + d0] = o2;
  }
}

// ---------- standalone GAT edge (layers 1..5; l=5 fuses cloud epilogue) ----------
__global__ __launch_bounds__(256) void k_gat_edge(
    const unsigned char* __restrict__ xl8, const bf16* __restrict__ xr,
    const float* __restrict__ att, const float* __restrict__ bias,
    const int* __restrict__ offs, const int* __restrict__ ssrc,
    bf16* __restrict__ out, float* __restrict__ statsOut,
    const float* __restrict__ p1a, const float* __restrict__ p1b,
    const float* __restrict__ p2a, const float* __restrict__ p2b,
    const bf16* __restrict__ h_bf,
    const float* __restrict__ colsum, const float* __restrict__ colsq,
    const float* __restrict__ lng, const float* __restrict__ lnb,
    const float* __restrict__ bng, const float* __restrict__ bnb,
    bf16* __restrict__ s_bf, float* __restrict__ zptr) {
  __shared__ float redS[4], redSS[4];
  edge_block(xl8, xr, att, bias, offs, ssrc, out, statsOut, redS, redSS,
             p1a, p1b, p2a, p2b, h_bf, colsum, colsq, lng, lnb, bng, bnb,
             s_bf, zptr);
}

// ---------- merged l=0 edge (1152 blocks) + cloud (2304 blocks, chunked) ----------
__global__ __launch_bounds__(256) void k_edge_cloud(
    const unsigned char* __restrict__ xl8, const bf16* __restrict__ xr,
    const float* __restrict__ att, const float* __restrict__ bias,
    const int* __restrict__ offs, const int* __restrict__ ssrc,
    bf16* __restrict__ out, float* __restrict__ statsOut,
    const float* __restrict__ g1f, const float* __restrict__ ep,
    const float* __restrict__ lin1b, const float* __restrict__ w3,
    float* __restrict__ p1a, float* __restrict__ p1b,
    float* __restrict__ p2a, float* __restrict__ p2b) {
  __shared__ float redS[4], redSS[4];
  if ((int)blockIdx.x < 1152) {
    edge_block(xl8, xr, att, bias, offs, ssrc, out, statsOut, redS, redSS,
               nullptr, nullptr, nullptr, nullptr, nullptr, nullptr, nullptr,
               nullptr, nullptr, nullptr, nullptr, nullptr, nullptr);
  } else {
    int w = (blockIdx.x - 1152) * 4 + (threadIdx.x >> 6);
    int c = (w >> 1) & 1;
    cloud_wave(g1f, ep, lin1b, w3, c ? p1b : p1a, c ? p2b : p2a,
               w, threadIdx.x & 63);
  }
}

__global__ void k_bn_out(const float* __restrict__ y, const float* __restrict__ colsum,
                         const float* __restrict__ colsq, const float* __restrict__ g,
                         const float* __restrict__ b, float* __restrict__ out) {
  int i = blockIdx.x * blockDim.x + threadIdx.x;
  if (i >= NN * DD) return;
  int d = i & 511;
  float mu = colsum[d] * (1.f / NN);
  float var = colsq[d] * (1.f / NN) - mu * mu;
  float inv = 1.f / sqrtf(fmaxf(var, 0.f) + 1e-5f);
  out[i] = (y[i] - mu) * inv * g[d] + b[d];
}

extern "C" void kernel_launch(void* const* d_in, const int* in_sizes, int n_in,
                              void* d_out, int out_size, void* d_ws, size_t ws_size,
                              hipStream_t stream) {
  const float* x = (const float*)d_in[0];
  const int* ei = (const int*)d_in[1];
  const float* xyz = (const float*)d_in[3];
  const float* x_proj_w = (const float*)d_in[5];
  const float* x_proj_b = (const float*)d_in[6];
  const float* gat_wl = (const float*)d_in[7];
  const float* gat_bl = (const float*)d_in[8];
  const float* gat_wr = (const float*)d_in[9];
  const float* gat_br = (const float*)d_in[10];
  const float* gat_att = (const float*)d_in[11];
  const float* gat_bias = (const float*)d_in[12];
  const float* gat_ln_g = (const float*)d_in[13];
  const float* gat_ln_b = (const float*)d_in[14];
  const float* cg_xyz_w = (const float*)d_in[15];
  const float* cg_bn_g = (const float*)d_in[16];
  const float* cg_bn_b = (const float*)d_in[17];
  const float* cg_lin1_w = (const float*)d_in[18];
  const float* cg_lin1_b = (const float*)d_in[19];
  const float* cg_ln_g = (const float*)d_in[20];
  const float* cg_ln_b = (const float*)d_in[21];
  const float* lin_w = (const float*)d_in[22];
  const float* lin_b = (const float*)d_in[23];
  const float* bn_g = (const float*)d_in[24];
  const float* bn_b = (const float*)d_in[25];

  const size_t ND = (size_t)NN * DD;
  char* w = (char*)d_ws;
  float* p1a = (float*)w;      w += ND * 4;  // alias: final y
  float* p2a = (float*)w;      w += ND * 4;
  float* p1b = (float*)w;      w += ND * 4;
  float* p2b = (float*)w;      w += ND * 4;
  float* g1f = (float*)w;      w += ND * 4;  // cloud g1 in f32 (no decode)
  bf16* h_bf = (bf16*)w;       w += ND * 2;  // alias: s_bf (after fused epi)
  bf16* xg_bf = (bf16*)w;      w += ND * 2;  // LN applied IN PLACE between layers
  bf16* xr_bf = (bf16*)w;      w += ND * 2;
  unsigned char* xl_f8 = (unsigned char*)w; w += ND;
  bf16* Wt = (bf16*)w;         w += (size_t)14 * NK * 2;
  float* eparam = (float*)w;   w += (size_t)BG * TRIU * 16;
  int* counts = (int*)w;       w += NN * 4;
  int* offs = (int*)w;         w += (NN + 4) * 4;
  int* cursor = (int*)w;       w += NN * 4;
  int* ssrc = (int*)w;         w += EREAL * 4;
  float* statsAll = (float*)w; w += 5 * 32 * 4;
  float* colsum = (float*)w;   w += 512 * 4;
  float* colsq = (float*)w;    w += 512 * 4;
  float* colsum2 = (float*)w;  w += 512 * 4;
  float* colsq2 = (float*)w;   w += 512 * 4;
  float* y = p1a;
  bf16* s_bf = h_bf;

  const int TPB = 256;
  const int ND_BLK = (int)((ND + TPB - 1) / TPB);

  k_wt<<<dim3(16, 16, 14), TPB, 0, stream>>>(gat_wl, gat_wr, cg_lin1_w, lin_w, Wt,
                                             counts, statsAll);
  k_xproj<<<ND_BLK, TPB, 0, stream>>>(x, x_proj_w, x_proj_b, ei, xyz, h_bf,
                                      counts, eparam);
  k_scan<<<1, 256, 0, stream>>>(counts, offs, cursor);

  // l=0 GEMM (xl,xr) + cloud g1 GEMM (f32) + edge scatter in ONE dispatch
  k_gemm_l0<<<1440, TPB, 0, stream>>>(h_bf, Wt, Wt + (size_t)6 * NK,
                                      gat_bl, gat_br, xr_bf, xl_f8,
                                      Wt + (size_t)12 * NK, g1f, colsum,
                                      ei, cursor, ssrc);
  // l=0 edge + chunk-split cloud in one dispatch (2x cloud parallelism)
  k_edge_cloud<<<1152 + 2304, TPB, 0, stream>>>(
      xl_f8, xr_bf, gat_att, gat_bias, offs, ssrc, xg_bf, statsAll,
      g1f, eparam, cg_lin1_b, cg_xyz_w, p1a, p1b, p2a, p2b);

  for (int l = 1; l < NLAYER; l++) {
    // in-place graph-LN (+ fused p2 col-reduce on the l==1 dispatch)
    k_ln<<<(l == 1) ? 1296 : 1152, TPB, 0, stream>>>(
        xg_bf, statsAll + 32 * (l - 1),
        gat_ln_g + (size_t)(l - 1) * DD, gat_ln_b + (size_t)(l - 1) * DD,
        (l == 1) ? p2a : nullptr, (l == 1) ? p2b : nullptr, colsum, colsq);
    k_gemm<<<576, TPB, 0, stream>>>(
        xg_bf, Wt + (size_t)l * NK, Wt + (size_t)(6 + l) * NK,
        gat_bl + l * DD, gat_br + l * DD, nullptr, nullptr, xr_bf,
        xl_f8, nullptr, nullptr, 4);
    float* sOut = (l < NLAYER - 1) ? statsAll + 32 * l : nullptr;
    bool last = (l == NLAYER - 1);
    k_gat_edge<<<NN / 4, TPB, 0, stream>>>(
        xl_f8, xr_bf, gat_att + l * DD, gat_bias + l * DD, offs, ssrc,
        xg_bf, sOut,
        last ? p1a : nullptr, last ? p1b : nullptr,
        last ? p2a : nullptr, last ? p2b : nullptr,
        last ? h_bf : nullptr,
        last ? colsum : nullptr, last ? colsq : nullptr,
        last ? cg_ln_g : nullptr, last ? cg_ln_b : nullptr,
        last ? cg_bn_g : nullptr, last ? cg_bn_b : nullptr,
        last ? s_bf : nullptr, last ? colsum2 : nullptr);
  }

  // final: y = s @ lin_w + lin_b (fp32) with fused column stats -> bn_out
  k_gemm<<<288, TPB, 0, stream>>>(
      s_bf, Wt + (size_t)13 * NK, Wt + (size_t)13 * NK, lin_b, lin_b,
      y, nullptr, nullptr, nullptr, colsum2, colsq2, 3);
  k_bn_out<<<ND_BLK, TPB, 0, stream>>>(y, colsum2, colsq2, bn_g, bn_b,
                                       (float*)d_out);
}

// Round 11
// 494.117 us; speedup vs baseline: 1.0600x; 1.0360x over previous
//
#include <hip/hip_runtime.h>
#include <hip/hip_bf16.h>

#define NN 4608
#define BG 48
#define NPG 96
#define DD 512
#define XDIM 16
#define EREAL 147456
#define NLAYER 6
#define NK 262144     // 512*512
#define TRIU 4656     // 96*97/2

typedef __hip_bfloat16 bf16;
typedef short short8 __attribute__((ext_vector_type(8)));
typedef short shortx4 __attribute__((ext_vector_type(4)));
typedef float f32x4 __attribute__((ext_vector_type(4)));
typedef float f32x2 __attribute__((ext_vector_type(2)));

__device__ __forceinline__ float s2f(short s) {
  return __uint_as_float(((unsigned int)(unsigned short)s) << 16);
}
__device__ __forceinline__ short f2bs(float f) {
  bf16 h = __float2bfloat16(f);
  short s;
  __builtin_memcpy(&s, &h, 2);
  return s;
}
__device__ __forceinline__ void f8x4(unsigned int w, float* o) {
  f32x2 a = __builtin_amdgcn_cvt_pk_f32_fp8(w, false);
  f32x2 b = __builtin_amdgcn_cvt_pk_f32_fp8(w, true);
  o[0] = a[0]; o[1] = a[1]; o[2] = b[0]; o[3] = b[1];
}

typedef const __attribute__((address_space(1))) unsigned int ga_u32;
typedef __attribute__((address_space(3))) unsigned int ls_u32;
__device__ __forceinline__ void gl16(const void* g, void* l) {
  __builtin_amdgcn_global_load_lds((ga_u32*)g, (ls_u32*)l, 16, 0, 0);
}

// ---------- weight transpose + bf16 convert; also zero counts & statsAll ----------
__global__ __launch_bounds__(256) void k_wt(const float* __restrict__ wl,
                                            const float* __restrict__ wr,
                                            const float* __restrict__ cg,
                                            const float* __restrict__ lin,
                                            bf16* __restrict__ Wt,
                                            int* __restrict__ counts,
                                            float* __restrict__ statsAll) {
  if (blockIdx.z == 0) {
    int id = (blockIdx.y * 16 + blockIdx.x) * 256 + threadIdx.x;
    if (id < NN) counts[id] = 0;
    if (id < 5 * 32) statsAll[id] = 0.f;
  }
  __shared__ float tile[32][33];
  int z = blockIdx.z;
  const float* src = (z < 6) ? wl + (size_t)z * NK
                   : (z < 12) ? wr + (size_t)(z - 6) * NK
                   : (z == 12) ? cg : lin;
  bf16* dst = Wt + (size_t)z * NK;
  int c = threadIdx.x & 31;
  int r0 = threadIdx.x >> 5;  // 0..7
  int bx = blockIdx.x * 32, by = blockIdx.y * 32;
#pragma unroll
  for (int i = 0; i < 4; i++) {
    int r = r0 + i * 8;
    tile[r][c] = src[(size_t)(by + r) * 512 + bx + c];  // [k][n]
  }
  __syncthreads();
#pragma unroll
  for (int i = 0; i < 4; i++) {
    int r = r0 + i * 8;  // n within tile
    dst[(size_t)(bx + r) * 512 + by + c] = __float2bfloat16(tile[c][r]);
  }
}

// ---------- x projection + edge histogram + cloud edge params ----------
__global__ void k_xproj(const float* __restrict__ x, const float* __restrict__ w,
                        const float* __restrict__ b, const int* __restrict__ ei,
                        const float* __restrict__ xyz,
                        bf16* __restrict__ h_bf, int* __restrict__ counts,
                        float* __restrict__ ep) {
  int i = blockIdx.x * blockDim.x + threadIdx.x;
  if (i >= NN * DD) return;
  if (i < EREAL) atomicAdd(&counts[ei[EREAL + i]], 1);
  if (i < NN * NPG) {
    int n = i / NPG, e = i - n * NPG;
    int p = n % NPG;
    if (e < NPG - p) {
      int g = n / NPG;
      int slot = g * TRIU + p * NPG - (p * (p - 1)) / 2 + e;
      int j = n + e;
      float dx = xyz[n * 3] - xyz[j * 3];
      float dy = xyz[n * 3 + 1] - xyz[j * 3 + 1];
      float dz = xyz[n * 3 + 2] - xyz[j * 3 + 2];
      float sq = dx * dx + dy * dy + dz * dz;
      float dist = (sq > 0.f) ? sqrtf(sq) : 0.f;
      float4 v;
      v.x = dx; v.y = dy; v.z = dz; v.w = __expf(-dist);
      *(float4*)&ep[(size_t)slot * 4] = v;
    }
  }
  int n = i >> 9, d = i & 511;
  float acc = b[d];
#pragma unroll
  for (int k = 0; k < XDIM; k++) acc += x[n * XDIM + k] * w[k * DD + d];
  h_bf[i] = __float2bfloat16(acc);
}

// ---------- edge sort: prefix scan of counts ----------
__global__ void k_scan(const int* __restrict__ counts, int* offsets, int* cursor) {
  __shared__ int part[256];
  int t = threadIdx.x;
  int base = t * 18;  // 4608/256
  int s = 0;
#pragma unroll
  for (int i = 0; i < 18; i++) s += counts[base + i];
  part[t] = s;
  __syncthreads();
  for (int off = 1; off < 256; off <<= 1) {
    int v = part[t];
    int u = (t >= off) ? part[t - off] : 0;
    __syncthreads();
    part[t] = v + u;
    __syncthreads();
  }
  int run = t ? part[t - 1] : 0;
#pragma unroll
  for (int i = 0; i < 18; i++) {
    offsets[base + i] = run;
    cursor[base + i] = run;
    run += counts[base + i];
  }
  if (t == 0) offsets[NN] = EREAL;
}

// ---------- graph-LN + relu, IN PLACE on xg; blocks >= 1152 do col-reduce ----------
// col-reduce (l==5 launch only) sums the two cloud partial buffers p2a+p2b.
__global__ __launch_bounds__(256) void k_ln(bf16* __restrict__ xg,
                                            const float* __restrict__ stats,
                                            const float* __restrict__ g,
                                            const float* __restrict__ b,
                                            const float* __restrict__ p2a,
                                            const float* __restrict__ p2b,
                                            float* __restrict__ colsum,
                                            float* __restrict__ colsq) {
  if ((int)blockIdx.x >= 1152) {  // fused col-reduce segment
    int r0 = (blockIdx.x - 1152) * 32;
    int c0 = threadIdx.x;
    float s0 = 0.f, q0 = 0.f, s1 = 0.f, q1 = 0.f;
    for (int r = r0; r < r0 + 32; ++r) {
      float v = p2a[(size_t)r * 512 + c0] + p2b[(size_t)r * 512 + c0];
      s0 += v; q0 += v * v;
      float w = p2a[(size_t)r * 512 + c0 + 256] + p2b[(size_t)r * 512 + c0 + 256];
      s1 += w; q1 += w * w;
    }
    atomicAdd(&colsum[c0], s0);
    atomicAdd(&colsq[c0], q0);
    atomicAdd(&colsum[c0 + 256], s1);
    atomicAdd(&colsq[c0 + 256], q1);
    return;
  }
  float s = 0.f, ss = 0.f;
#pragma unroll
  for (int i = 0; i < 16; i++) { s += stats[i]; ss += stats[16 + i]; }
  const float invM = 1.f / ((float)NN * (float)DD);
  float mu = s * invM;
  float var = ss * invM - mu * mu;
  float sd = sqrtf(fmaxf(var, 0.f));
  float inv = 1.f / (sd + 1e-5f);
  int i = blockIdx.x * 256 + threadIdx.x;
  int base = i * 8;
  int d0 = base & 511;
  short8 raw = *(const short8*)&xg[base];
  short8 pk;
#pragma unroll
  for (int k = 0; k < 8; k++) {
    float t = fmaxf((s2f(raw[k]) - mu) * inv * g[d0 + k] + b[d0 + k], 0.f);
    pk[k] = f2bs(t);
  }
  *(short8*)&xg[base] = pk;
}

// ---------- shared GEMM tile body: BK=64 dbuf, XOR-swizzled LDS, swapped MFMA ----
__device__ __forceinline__ void gemm_tile(
    const bf16* __restrict__ Abf, const bf16* __restrict__ B,
    const float* __restrict__ bias,
    float* __restrict__ C, bf16* __restrict__ Cb, unsigned char* __restrict__ Cf8,
    float* __restrict__ csum, float* __restrict__ csq,
    int m0, int n0, bf16* As, bf16* Bs, float* cs, float* cq) {
  int tid = threadIdx.x;
  int lane = tid & 63, wid = tid >> 6;
  int mh = (wid >> 1) * 64, nh = (wid & 1) * 32;
  int l15 = lane & 15, quad = lane >> 4;
  int lr8 = lane >> 3, ls8 = lane & 7;
  int c16l = ls8 ^ lr8;        // inverse-swizzled 16B chunk for staging
  int swzr = (l15 & 7) * 8;    // read-side swizzle term (elements)

  if (csum && tid < 64) { cs[tid] = 0.f; cq[tid] = 0.f; }

  const bf16* aSrc = Abf + (size_t)(m0 + wid * 32 + lr8) * 512 + c16l * 8;
  const bf16* bSrc = B   + (size_t)(n0 + wid * 16 + lr8) * 512 + c16l * 8;

#define STAGE(bi, kt) do {                                                   \
    gl16(aSrc + (kt) * 64,            As + (bi) * 8192 + (wid * 32     ) * 64); \
    gl16(aSrc + (kt) * 64 +  8 * 512, As + (bi) * 8192 + (wid * 32 +  8) * 64); \
    gl16(aSrc + (kt) * 64 + 16 * 512, As + (bi) * 8192 + (wid * 32 + 16) * 64); \
    gl16(aSrc + (kt) * 64 + 24 * 512, As + (bi) * 8192 + (wid * 32 + 24) * 64); \
    gl16(bSrc + (kt) * 64,            Bs + (bi) * 4096 + (wid * 16     ) * 64); \
    gl16(bSrc + (kt) * 64 +  8 * 512, Bs + (bi) * 4096 + (wid * 16 +  8) * 64); \
  } while (0)

  f32x4 acc[4][2];
#pragma unroll
  for (int mt = 0; mt < 4; mt++)
#pragma unroll
    for (int nt = 0; nt < 2; nt++) acc[mt][nt] = (f32x4)0.f;

  STAGE(0, 0);
  __syncthreads();  // drains vmcnt(0) -> buf0 ready

#pragma unroll
  for (int kt = 0; kt < 8; kt++) {
    const int cur = kt & 1;
    if (kt < 7) STAGE(cur ^ 1, kt + 1);  // prefetch overlaps ds_read+MFMA
    short8 af[2][4], bfr[2][2];
#pragma unroll
    for (int kk = 0; kk < 2; kk++) {
#pragma unroll
      for (int mt = 0; mt < 4; mt++)
        af[kk][mt] = *(const short8*)&As[cur * 8192 + (mh + mt * 16 + l15) * 64 +
                                        (((kk * 4 + quad) * 8) ^ swzr)];
#pragma unroll
      for (int nt = 0; nt < 2; nt++)
        bfr[kk][nt] = *(const short8*)&Bs[cur * 4096 + (nh + nt * 16 + l15) * 64 +
                                         (((kk * 4 + quad) * 8) ^ swzr)];
    }
#pragma unroll
    for (int kk = 0; kk < 2; kk++)
#pragma unroll
      for (int mt = 0; mt < 4; mt++)
#pragma unroll
        for (int nt = 0; nt < 2; nt++)
          acc[mt][nt] = __builtin_amdgcn_mfma_f32_16x16x32_bf16(
              bfr[kk][nt], af[kk][mt], acc[mt][nt], 0, 0, 0);
    __syncthreads();
  }
#undef STAGE

  // D-layout (swapped operands): m = mh+mt*16+l15, n = nh+nt*16+quad*4+r
  float colS[2][4] = {{0.f,0.f,0.f,0.f},{0.f,0.f,0.f,0.f}};
  float colQ[2][4] = {{0.f,0.f,0.f,0.f},{0.f,0.f,0.f,0.f}};
  float bv[2][4] = {{0.f,0.f,0.f,0.f},{0.f,0.f,0.f,0.f}};
#pragma unroll
  for (int nt = 0; nt < 2; nt++) {
    if (bias) {
      float4 b4 = *(const float4*)&bias[n0 + nh + nt * 16 + quad * 4];
      bv[nt][0] = b4.x; bv[nt][1] = b4.y; bv[nt][2] = b4.z; bv[nt][3] = b4.w;
    }
  }
#pragma unroll
  for (int mt = 0; mt < 4; mt++) {
    int row = m0 + mh + mt * 16 + l15;
#pragma unroll
    for (int nt = 0; nt < 2; nt++) {
      int col0 = n0 + nh + nt * 16 + quad * 4;
      float v[4];
#pragma unroll
      for (int r2 = 0; r2 < 4; r2++) {
        v[r2] = acc[mt][nt][r2] + bv[nt][r2];
        if (csum) { colS[nt][r2] += v[r2]; colQ[nt][r2] += v[r2] * v[r2]; }
      }
      if (C) {
        float4 o; o.x = v[0]; o.y = v[1]; o.z = v[2]; o.w = v[3];
        *(float4*)&C[(size_t)row * 512 + col0] = o;
      }
      if (Cb) {
        shortx4 o;
#pragma unroll
        for (int r2 = 0; r2 < 4; r2++) o[r2] = f2bs(v[r2]);
        *(shortx4*)&Cb[(size_t)row * 512 + col0] = o;
      }
      if (Cf8) {
        unsigned int u = __builtin_amdgcn_cvt_pk_fp8_f32(v[0], v[1], 0, false);
        u = __builtin_amdgcn_cvt_pk_fp8_f32(v[2], v[3], u, true);
        *(unsigned int*)&Cf8[(size_t)row * 512 + col0] = u;
      }
    }
  }
  if (csum) {
#pragma unroll
    for (int nt = 0; nt < 2; nt++)
#pragma unroll
      for (int r2 = 0; r2 < 4; r2++) {
        atomicAdd(&cs[nh + nt * 16 + quad * 4 + r2], colS[nt][r2]);
        atomicAdd(&cq[nh + nt * 16 + quad * 4 + r2], colQ[nt][r2]);
      }
    __syncthreads();
    if (tid < 64) {
      atomicAdd(&csum[n0 + tid], cs[tid]);
      atomicAdd(&csq[n0 + tid], cq[tid]);
    }
  }
}

// ---------- standalone GEMM (GAT l>=1 and final): nzl=4 (2 B slots) or 3 ----------
__global__ __launch_bounds__(256) void k_gemm(
    const bf16* __restrict__ Abf,
    const bf16* __restrict__ B0, const bf16* __restrict__ B1,
    const float* __restrict__ bias0, const float* __restrict__ bias1,
    float* __restrict__ C0,
    bf16* __restrict__ Cb0, bf16* __restrict__ Cb1,
    unsigned char* __restrict__ Cf8_0,
    float* __restrict__ csum, float* __restrict__ csq, int nzl) {
  __shared__ __align__(16) bf16 As[2 * 128 * 64];
  __shared__ __align__(16) bf16 Bs[2 * 64 * 64];
  __shared__ float cs[64], cq[64];
  int cpx = gridDim.x >> 3;
  int wgid = (blockIdx.x & 7) * cpx + (blockIdx.x >> 3);
  int mi = wgid >> nzl;
  int r = wgid & ((1 << nzl) - 1);
  int z = r >> 3;  // 0 when nzl==3
  int m0 = mi * 128, n0 = (r & 7) * 64;
  gemm_tile(Abf, z ? B1 : B0, z ? bias1 : bias0,
            z ? nullptr : C0, z ? Cb1 : Cb0, z ? nullptr : Cf8_0,
            csum, csq, m0, n0, As, Bs, cs, cq);
}

// ---------- merged l=0 dispatch: GAT xl/xr (576) + cloud g1 f32 (288) + scatter (576) ----
__global__ __launch_bounds__(256) void k_gemm_l0(
    const bf16* __restrict__ h_bf,
    const bf16* __restrict__ Bl, const bf16* __restrict__ Br,
    const float* __restrict__ biasl, const float* __restrict__ biasr,
    bf16* __restrict__ xr_bf, unsigned char* __restrict__ xl_f8,
    const bf16* __restrict__ Bg1, float* __restrict__ g1f,
    float* __restrict__ zptr,
    const int* __restrict__ ei, int* __restrict__ cursor, int* __restrict__ ssrc) {
  __shared__ __align__(16) bf16 As[2 * 128 * 64];
  __shared__ __align__(16) bf16 Bs[2 * 64 * 64];
  int b = blockIdx.x;
  if (b < 576) {  // GAT l=0 segment
    int cpx = 576 >> 3;
    int wgid = (b & 7) * cpx + (b >> 3);
    int mi = wgid >> 4;
    int r = wgid & 15;
    int z = r >> 3;
    int m0 = mi * 128, n0 = (r & 7) * 64;
    gemm_tile(h_bf, z ? Br : Bl, z ? biasr : biasl,
              nullptr, z ? xr_bf : nullptr, z ? nullptr : xl_f8,
              nullptr, nullptr, m0, n0, As, Bs, nullptr, nullptr);
  } else if (b < 864) {  // cloud g1 segment, f32 out (also zeroes colsum/colsq)
    int b2 = b - 576;
    if (b2 == 0) {
      for (int i = threadIdx.x; i < 1024; i += 256) zptr[i] = 0.f;
    }
    int cpx = 288 >> 3;
    int wgid = (b2 & 7) * cpx + (b2 >> 3);
    int mi = wgid >> 3;
    int r = wgid & 7;
    int m0 = mi * 128, n0 = r * 64;
    gemm_tile(h_bf, Bg1, nullptr, g1f, nullptr, nullptr,
              nullptr, nullptr, m0, n0, As, Bs, nullptr, nullptr);
  } else {  // counting-sort scatter segment (576 blocks x 256 = EREAL)
    int e = (b - 864) * 256 + threadIdx.x;
    int s = ei[e], d = ei[EREAL + e];
    int pos = atomicAdd(&cursor[d], 1);
    ssrc[pos] = s;
  }
}

// ---------- GAT edge block body; optional fused cloud epilogue (l=5) ----------
__device__ __forceinline__ void edge_block(
    const unsigned char* __restrict__ xl8, const bf16* __restrict__ xr,
    const float* __restrict__ att, const float* __restrict__ bias,
    const int* __restrict__ offs, const int* __restrict__ ssrc,
    bf16* __restrict__ out, float* __restrict__ statsOut,
    float* redS, float* redSS,
    const float* __restrict__ p1a, const float* __restrict__ p1b,
    const float* __restrict__ p2a, const float* __restrict__ p2b,
    const bf16* __restrict__ h_bf,
    const float* __restrict__ colsum, const float* __restrict__ colsq,
    const float* __restrict__ lng, const float* __restrict__ lnb,
    const float* __restrict__ bng, const float* __restrict__ bnb,
    bf16* __restrict__ s_bf, float* __restrict__ zptr) {
  if (zptr && blockIdx.x == 0) {
    for (int i = threadIdx.x; i < 1024; i += 256) zptr[i] = 0.f;
  }
  int wave = (blockIdx.x * blockDim.x + threadIdx.x) >> 6;
  int lane = threadIdx.x & 63;
  int wid = threadIdx.x >> 6;
  if (wave < NN) {
    int n = wave;
    int base = lane * 8;
    float xrv[8], attv[8], acc[8];
    short8 xr8 = *(const short8*)&xr[(size_t)n * 512 + base];
#pragma unroll
    for (int k = 0; k < 8; k++) {
      xrv[k] = s2f(xr8[k]);
      attv[k] = att[base + k];
    }
    float m0, lsum;
    {
      uint2 q = *(const uint2*)&xl8[(size_t)n * 512 + base];
      float xs[8];
      f8x4(q.x, xs);
      f8x4(q.y, xs + 4);
      float sc0 = 0.f;
#pragma unroll
      for (int k = 0; k < 8; k++) {
        acc[k] = xs[k];
        float t = xs[k] + xrv[k];
        t = (t > 0.f) ? t : 0.2f * t;
        sc0 += attv[k] * t;
      }
#pragma unroll
      for (int off = 32; off >= 1; off >>= 1) sc0 += __shfl_xor(sc0, off, 64);
      m0 = sc0;
      lsum = 1.f;
    }
    int e0 = offs[n], e1 = offs[n + 1];
    int e = e0;
    for (; e + 3 < e1; e += 4) {
      int s0 = ssrc[e], s1 = ssrc[e + 1], s2 = ssrc[e + 2], s3 = ssrc[e + 3];
      uint2 q0 = *(const uint2*)&xl8[(size_t)s0 * 512 + base];
      uint2 q1 = *(const uint2*)&xl8[(size_t)s1 * 512 + base];
      uint2 q2 = *(const uint2*)&xl8[(size_t)s2 * 512 + base];
      uint2 q3 = *(const uint2*)&xl8[(size_t)s3 * 512 + base];
      float x0[8], x1[8], x2[8], x3[8];
      f8x4(q0.x, x0); f8x4(q0.y, x0 + 4);
      f8x4(q1.x, x1); f8x4(q1.y, x1 + 4);
      f8x4(q2.x, x2); f8x4(q2.y, x2 + 4);
      f8x4(q3.x, x3); f8x4(q3.y, x3 + 4);
      float c0 = 0.f, c1 = 0.f, c2 = 0.f, c3 = 0.f;
#pragma unroll
      for (int k = 0; k < 8; k++) {
        float t0 = x0[k] + xrv[k]; t0 = (t0 > 0.f) ? t0 : 0.2f * t0; c0 += attv[k] * t0;
        float t1 = x1[k] + xrv[k]; t1 = (t1 > 0.f) ? t1 : 0.2f * t1; c1 += attv[k] * t1;
        float t2 = x2[k] + xrv[k]; t2 = (t2 > 0.f) ? t2 : 0.2f * t2; c2 += attv[k] * t2;
        float t3 = x3[k] + xrv[k]; t3 = (t3 > 0.f) ? t3 : 0.2f * t3; c3 += attv[k] * t3;
      }
#pragma unroll
      for (int off = 32; off >= 1; off >>= 1) {
        c0 += __shfl_xor(c0, off, 64);
        c1 += __shfl_xor(c1, off, 64);
        c2 += __shfl_xor(c2, off, 64);
        c3 += __shfl_xor(c3, off, 64);
      }
      float p0 = __expf(c0 - m0), pp1 = __expf(c1 - m0);
      float pp2 = __expf(c2 - m0), p3 = __expf(c3 - m0);
      lsum += p0 + pp1 + pp2 + p3;
#pragma unroll
      for (int k = 0; k < 8; k++)
        acc[k] += p0 * x0[k] + pp1 * x1[k] + pp2 * x2[k] + p3 * x3[k];
    }
    for (; e < e1; ++e) {
      int s0 = ssrc[e];
      uint2 q = *(const uint2*)&xl8[(size_t)s0 * 512 + base];
      float x0[8];
      f8x4(q.x, x0);
      f8x4(q.y, x0 + 4);
      float sc0 = 0.f;
#pragma unroll
      for (int k = 0; k < 8; k++) {
        float t0 = x0[k] + xrv[k];
        t0 = (t0 > 0.f) ? t0 : 0.2f * t0;
        sc0 += attv[k] * t0;
      }
#pragma unroll
      for (int off = 32; off >= 1; off >>= 1) sc0 += __shfl_xor(sc0, off, 64);
      float p0 = __expf(sc0 - m0);
      lsum += p0;
#pragma unroll
      for (int k = 0; k < 8; k++) acc[k] += p0 * x0[k];
    }
    float inv = 1.f / lsum;
    float o[8];
    float s = 0.f, ss = 0.f;
    short8 o8;
#pragma unroll
    for (int k = 0; k < 8; k++) {
      o[k] = acc[k] * inv + bias[base + k];
      s += o[k];
      ss += o[k] * o[k];
      o8[k] = f2bs(o[k]);
    }
    *(short8*)&out[(size_t)n * 512 + base] = o8;
    if (statsOut) {
#pragma unroll
      for (int off = 32; off >= 1; off >>= 1) {
        s += __shfl_xor(s, off, 64);
        ss += __shfl_xor(ss, off, 64);
      }
      if (lane == 0) { redS[wid] = s; redSS[wid] = ss; }
    }
    if (s_bf) {
      // fused cloud epilogue: ln_row(p1a+p1b) + bn(p2a+p2b) + fuse -> s_bf
      size_t rb = (size_t)n * 512 + base;
      float v[8];
      float sp = 0.f;
#pragma unroll
      for (int k = 0; k < 8; k++) {
        v[k] = p1a[rb + k] + p1b[rb + k];
        sp += v[k];
      }
#pragma unroll
      for (int off = 32; off >= 1; off >>= 1) sp += __shfl_xor(sp, off, 64);
      float mu = sp * (1.f / 512.f);
      float ssp = 0.f;
#pragma unroll
      for (int k = 0; k < 8; k++) {
        float t = v[k] - mu;
        ssp += t * t;
      }
#pragma unroll
      for (int off = 32; off >= 1; off >>= 1) ssp += __shfl_xor(ssp, off, 64);
      float linv = 1.f / sqrtf(ssp * (1.f / 512.f) + 1e-5f);
      short8 hb = *(const short8*)&h_bf[rb];
      short8 e8;
#pragma unroll
      for (int k = 0; k < 8; k++) {
        int d = base + k;
        float ln1 = (v[k] - mu) * linv * lng[d] + lnb[d];
        float cmu = colsum[d] * (1.f / NN);
        float cvar = colsq[d] * (1.f / NN) - cmu * cmu;
        float cinv = 1.f / sqrtf(fmaxf(cvar, 0.f) + 1e-5f);
        float p2v = p2a[rb + k] + p2b[rb + k];
        float bnv = (p2v - cmu) * cinv * bng[d] + bnb[d];
        float outv = 2.f * s2f(hb[k]) + s2f(o8[k]) + ln1 + bnv;
        e8[k] = f2bs(outv);
      }
      *(short8*)&s_bf[rb] = e8;
    }
  }
  if (statsOut) {
    __syncthreads();
    if (threadIdx.x == 0) {
      float a = redS[0] + redS[1] + redS[2] + redS[3];
      float b = redSS[0] + redSS[1] + redSS[2] + redSS[3];
      int slot = blockIdx.x & 15;
      atomicAdd(&statsOut[slot], a);
      atomicAdd(&statsOut[16 + slot], b);
    }
  }
}

// ---------- cloud wave body: (pair, qh, chunk) per wave; f32 g1; 4 dims/lane ----
__device__ __forceinline__ void cloud_wave(
    const float* __restrict__ g1f, const float* __restrict__ ep,
    const float* __restrict__ lin1b, const float* __restrict__ w3,
    float* __restrict__ p1c, float* __restrict__ p2c, int w, int lane) {
  int qh = w & 1;
  int c = (w >> 1) & 1;
  int pi = w >> 2;              // [0, 2304)
  int g = pi / 48, pp = pi % 48;
  int d0 = qh * 256 + lane * 4;
  float4 bb4 = *(const float4*)&lin1b[d0];
  float4 w04 = *(const float4*)&w3[d0];
  float4 w14 = *(const float4*)&w3[512 + d0];
  float4 w24 = *(const float4*)&w3[1024 + d0];
  float bb[4] = {bb4.x, bb4.y, bb4.z, bb4.w};
  float w0[4] = {w04.x, w04.y, w04.z, w04.w};
  float w1[4] = {w14.x, w14.y, w14.z, w14.w};
  float w2[4] = {w24.x, w24.y, w24.z, w24.w};

#pragma unroll
  for (int half = 0; half < 2; half++) {
    int p = half ? (NPG - 1 - pp) : pp;
    int n = g * NPG + p;
    int cnt = NPG - p;
    int h = cnt >> 1;
    int eBeg = c ? h : 0;
    int eEnd = c ? cnt : h;
    int slot0 = g * TRIU + p * NPG - (p * (p - 1)) / 2;
    const float* grow = &g1f[(size_t)n * 512 + d0];
    float4 g4 = *(const float4*)grow;
    float gi[4] = {g4.x, g4.y, g4.z, g4.w};
    float a1[4] = {0.f,0.f,0.f,0.f}, a2[4] = {0.f,0.f,0.f,0.f};
    float b1[4] = {0.f,0.f,0.f,0.f}, b2[4] = {0.f,0.f,0.f,0.f};
    int e = eBeg;
    for (; e + 3 < eEnd; e += 4) {
      int sb = __builtin_amdgcn_readfirstlane(slot0 + e);  // wave-uniform -> s_load
      float4 pa = *(const float4*)&ep[(size_t)sb * 4];
      float4 pb = *(const float4*)&ep[(size_t)(sb + 1) * 4];
      float4 pc = *(const float4*)&ep[(size_t)(sb + 2) * 4];
      float4 pd = *(const float4*)&ep[(size_t)(sb + 3) * 4];
      float4 xa = *(const float4*)&grow[(size_t)e * 512];
      float4 xb = *(const float4*)&grow[(size_t)(e + 1) * 512];
      float4 xc = *(const float4*)&grow[(size_t)(e + 2) * 512];
      float4 xd = *(const float4*)&grow[(size_t)(e + 3) * 512];
      float xaf[4] = {xa.x, xa.y, xa.z, xa.w};
      float xbf[4] = {xb.x, xb.y, xb.z, xb.w};
      float xcf[4] = {xc.x, xc.y, xc.z, xc.w};
      float xdf[4] = {xd.x, xd.y, xd.z, xd.w};
      float t;
#pragma unroll
      for (int k = 0; k < 4; k++) {
        t = fmaf(pa.w, gi[k] - xaf[k], bb[k]); a1[k] += fmaxf(t, 0.f);
        t = fmaf(pb.w, gi[k] - xbf[k], bb[k]); b1[k] += fmaxf(t, 0.f);
        t = fmaf(pc.w, gi[k] - xcf[k], bb[k]); a1[k] += fmaxf(t, 0.f);
        t = fmaf(pd.w, gi[k] - xdf[k], bb[k]); b1[k] += fmaxf(t, 0.f);
        t = pa.x * w0[k] + pa.y * w1[k] + pa.z * w2[k]; a2[k] += fmaxf(t, 0.f);
        t = pb.x * w0[k] + pb.y * w1[k] + pb.z * w2[k]; b2[k] += fmaxf(t, 0.f);
        t = pc.x * w0[k] + pc.y * w1[k] + pc.z * w2[k]; a2[k] += fmaxf(t, 0.f);
        t = pd.x * w0[k] + pd.y * w1[k] + pd.z * w2[k]; b2[k] += fmaxf(t, 0.f);
      }
    }
    for (; e < eEnd; ++e) {
      float4 pa = *(const float4*)&ep[(size_t)(slot0 + e) * 4];
      float4 xa = *(const float4*)&grow[(size_t)e * 512];
      float xaf[4] = {xa.x, xa.y, xa.z, xa.w};
      float t;
#pragma unroll
      for (int k = 0; k < 4; k++) {
        t = fmaf(pa.w, gi[k] - xaf[k], bb[k]); a1[k] += fmaxf(t, 0.f);
        t = pa.x * w0[k] + pa.y * w1[k] + pa.z * w2[k]; a2[k] += fmaxf(t, 0.f);
      }
    }
    float4 o1, o2;
    o1.x = a1[0] + b1[0]; o1.y = a1[1] + b1[1];
    o1.z = a1[2] + b1[2]; o1.w = a1[3] + b1[3];
    o2.x = a2[0] + b2[0]; o2.y = a2[1] + b2[1];
    o2.z = a2[2] + b2[2]; o2.w = a2[3] + b2[3];
    *(float4*)&p1c[(size_t)n * 512 + d0] = o1;
    *(float4*)&p2c[(size_t)n * 512 + d0] = o2;
  }
}

// ---------- GAT edge (all layers). Blocks >= 1152 run a cloud chunk (l<4). ----
// Cloud chunk overlaps edge work inside the dispatch (no LDS -> full packing).
__global__ __launch_bounds__(256) void k_gat_edge(
    const unsigned char* __restrict__ xl8, const bf16* __restrict__ xr,
    const float* __restrict__ att, const float* __restrict__ bias,
    const int* __restrict__ offs, const int* __restrict__ ssrc,
    bf16* __restrict__ out, float* __restrict__ statsOut,
    const float* __restrict__ p1a, const float* __restrict__ p1b,
    const float* __restrict__ p2a, const float* __restrict__ p2b,
    const bf16* __restrict__ h_bf,
    const float* __restrict__ colsum, const float* __restrict__ colsq,
    const float* __restrict__ lng, const float* __restrict__ lnb,
    const float* __restrict__ bng, const float* __restrict__ bnb,
    bf16* __restrict__ s_bf, float* __restrict__ zptr,
    const float* __restrict__ g1f, const float* __restrict__ ep,
    const float* __restrict__ lin1b_c, const float* __restrict__ w3,
    float* __restrict__ cp1a, float* __restrict__ cp1b,
    float* __restrict__ cp2a, float* __restrict__ cp2b, int chunkStart) {
  __shared__ float redS[4], redSS[4];
  if ((int)blockIdx.x < 1152) {
    edge_block(xl8, xr, att, bias, offs, ssrc, out, statsOut, redS, redSS,
               p1a, p1b, p2a, p2b, h_bf, colsum, colsq, lng, lnb, bng, bnb,
               s_bf, zptr);
  } else {
    int w = ((int)blockIdx.x - 1152 + chunkStart) * 4 + (threadIdx.x >> 6);
    int c = (w >> 1) & 1;
    cloud_wave(g1f, ep, lin1b_c, w3, c ? cp1b : cp1a, c ? cp2b : cp2a,
               w, threadIdx.x & 63);
  }
}

__global__ void k_bn_out(const float* __restrict__ y, const float* __restrict__ colsum,
                         const float* __restrict__ colsq, const float* __restrict__ g,
                         const float* __restrict__ b, float* __restrict__ out) {
  int i = blockIdx.x * blockDim.x + threadIdx.x;
  if (i >= NN * DD) return;
  int d = i & 511;
  float mu = colsum[d] * (1.f / NN);
  float var = colsq[d] * (1.f / NN) - mu * mu;
  float inv = 1.f / sqrtf(fmaxf(var, 0.f) + 1e-5f);
  out[i] = (y[i] - mu) * inv * g[d] + b[d];
}

extern "C" void kernel_launch(void* const* d_in, const int* in_sizes, int n_in,
                              void* d_out, int out_size, void* d_ws, size_t ws_size,
                              hipStream_t stream) {
  const float* x = (const float*)d_in[0];
  const int* ei = (const int*)d_in[1];
  const float* xyz = (const float*)d_in[3];
  const float* x_proj_w = (const float*)d_in[5];
  const float* x_proj_b = (const float*)d_in[6];
  const float* gat_wl = (const float*)d_in[7];
  const float* gat_bl = (const float*)d_in[8];
  const float* gat_wr = (const float*)d_in[9];
  const float* gat_br = (const float*)d_in[10];
  const float* gat_att = (const float*)d_in[11];
  const float* gat_bias = (const float*)d_in[12];
  const float* gat_ln_g = (const float*)d_in[13];
  const float* gat_ln_b = (const float*)d_in[14];
  const float* cg_xyz_w = (const float*)d_in[15];
  const float* cg_bn_g = (const float*)d_in[16];
  const float* cg_bn_b = (const float*)d_in[17];
  const float* cg_lin1_w = (const float*)d_in[18];
  const float* cg_lin1_b = (const float*)d_in[19];
  const float* cg_ln_g = (const float*)d_in[20];
  const float* cg_ln_b = (const float*)d_in[21];
  const float* lin_w = (const float*)d_in[22];
  const float* lin_b = (const float*)d_in[23];
  const float* bn_g = (const float*)d_in[24];
  const float* bn_b = (const float*)d_in[25];

  const size_t ND = (size_t)NN * DD;
  char* w = (char*)d_ws;
  float* p1a = (float*)w;      w += ND * 4;  // alias: final y
  float* p2a = (float*)w;      w += ND * 4;
  float* p1b = (float*)w;      w += ND * 4;
  float* p2b = (float*)w;      w += ND * 4;
  float* g1f = (float*)w;      w += ND * 4;  // cloud g1 in f32 (no decode)
  bf16* h_bf = (bf16*)w;       w += ND * 2;  // alias: s_bf (after fused epi)
  bf16* xg_bf = (bf16*)w;      w += ND * 2;  // LN applied IN PLACE between layers
  bf16* xr_bf = (bf16*)w;      w += ND * 2;
  unsigned char* xl_f8 = (unsigned char*)w; w += ND;
  bf16* Wt = (bf16*)w;         w += (size_t)14 * NK * 2;
  float* eparam = (float*)w;   w += (size_t)BG * TRIU * 16;
  int* counts = (int*)w;       w += NN * 4;
  int* offs = (int*)w;         w += (NN + 4) * 4;
  int* cursor = (int*)w;       w += NN * 4;
  int* ssrc = (int*)w;         w += EREAL * 4;
  float* statsAll = (float*)w; w += 5 * 32 * 4;
  float* colsum = (float*)w;   w += 512 * 4;
  float* colsq = (float*)w;    w += 512 * 4;
  float* colsum2 = (float*)w;  w += 512 * 4;
  float* colsq2 = (float*)w;   w += 512 * 4;
  float* y = p1a;
  bf16* s_bf = h_bf;

  const int TPB = 256;
  const int ND_BLK = (int)((ND + TPB - 1) / TPB);

  k_wt<<<dim3(16, 16, 14), TPB, 0, stream>>>(gat_wl, gat_wr, cg_lin1_w, lin_w, Wt,
                                             counts, statsAll);
  k_xproj<<<ND_BLK, TPB, 0, stream>>>(x, x_proj_w, x_proj_b, ei, xyz, h_bf,
                                      counts, eparam);
  k_scan<<<1, 256, 0, stream>>>(counts, offs, cursor);

  // l=0 GEMM (xl,xr) + cloud g1 GEMM (f32) + edge scatter in ONE dispatch
  k_gemm_l0<<<1440, TPB, 0, stream>>>(h_bf, Wt, Wt + (size_t)6 * NK,
                                      gat_bl, gat_br, xr_bf, xl_f8,
                                      Wt + (size_t)12 * NK, g1f, colsum,
                                      ei, cursor, ssrc);

  for (int l = 0; l < NLAYER; l++) {
    if (l > 0) {
      // in-place graph-LN (+ fused p2 col-reduce on the l==5 dispatch,
      // after all cloud chunks which end at edge l=3)
      k_ln<<<(l == 5) ? 1296 : 1152, TPB, 0, stream>>>(
          xg_bf, statsAll + 32 * (l - 1),
          gat_ln_g + (size_t)(l - 1) * DD, gat_ln_b + (size_t)(l - 1) * DD,
          p2a, p2b, colsum, colsq);
      k_gemm<<<576, TPB, 0, stream>>>(
          xg_bf, Wt + (size_t)l * NK, Wt + (size_t)(6 + l) * NK,
          gat_bl + l * DD, gat_br + l * DD, nullptr, nullptr, xr_bf,
          xl_f8, nullptr, nullptr, 4);
    }
    float* sOut = (l < NLAYER - 1) ? statsAll + 32 * l : nullptr;
    bool last = (l == NLAYER - 1);
    bool hasCloud = (l < 4);  // 4 chunks x 576 blocks cover all 2304 cloud blocks
    k_gat_edge<<<1152 + (hasCloud ? 576 : 0), TPB, 0, stream>>>(
        xl_f8, xr_bf, gat_att + l * DD, gat_bias + l * DD, offs, ssrc,
        xg_bf, sOut,
        last ? p1a : nullptr, last ? p1b : nullptr,
        last ? p2a : nullptr, last ? p2b : nullptr,
        last ? h_bf : nullptr,
        last ? colsum : nullptr, last ? colsq : nullptr,
        last ? cg_ln_g : nullptr, last ? cg_ln_b : nullptr,
        last ? cg_bn_g : nullptr, last ? cg_bn_b : nullptr,
        last ? s_bf : nullptr, last ? colsum2 : nullptr,
        hasCloud ? g1f : nullptr, eparam, cg_lin1_b, cg_xyz_w,
        p1a, p1b, p2a, p2b, l * 576);
  }

  // final: y = s @ lin_w + lin_b (fp32) with fused column stats -> bn_out
  k_gemm<<<288, TPB, 0, stream>>>(
      s_bf, Wt + (size_t)13 * NK, Wt + (size_t)13 * NK, lin_b, lin_b,
      y, nullptr, nullptr, nullptr, colsum2, colsq2, 3);
  k_bn_out<<<ND_BLK, TPB, 0, stream>>>(y, colsum2, colsq2, bn_g, bn_b,
                                       (float*)d_out);
}